// Round 1
// baseline (2210.850 us; speedup 1.0000x reference)
//
#include <hip/hip_runtime.h>

// GCN forward: BN(x) -> [GCNConv+ReLU] x3 -> BN -> Linear+ReLU
// N=100000 nodes, E=600000 edges, dims 256->128->128->128->64, all fp32.
//
// Structure:
//   deg/norm precompute (atomics) -> BN-stats(x) -> fold BN into W0 ->
//   GEMM0 -> AGG0 -> GEMM1(fused relu+b0 on read) -> AGG1 -> GEMM2 -> AGG2 ->
//   BN-stats(relu(agg2+b2)) -> fold BN into pW -> GEMM3 (fused in+out) -> d_out

constexpr int NN     = 100000;
constexpr int NEDGE  = 600000;
constexpr int INDIM  = 256;
constexpr int HD     = 128;   // hidden dim for all three conv layers
constexpr int OUTD   = 64;
#define EPSV 1e-5f

// ---------------------------------------------------------------- utilities
__device__ __forceinline__ void atomAdd(float* p, float v) {
    unsafeAtomicAdd(p, v);   // native global_atomic_add_f32 on gfx950
}

// ------------------------------------------------------------ degree kernel
__global__ __launch_bounds__(256) void deg_k(const int* __restrict__ dst,
                                             const float* __restrict__ ew,
                                             float* __restrict__ deg, int e) {
    int i = blockIdx.x * blockDim.x + threadIdx.x;
    if (i < e) atomAdd(&deg[dst[i]], ew[i]);
}

// -------------------------------------------------------------- norm kernel
__global__ __launch_bounds__(256) void norm_k(const int* __restrict__ src,
                                              const int* __restrict__ dst,
                                              const float* __restrict__ ew,
                                              const float* __restrict__ deg,
                                              float* __restrict__ nrm, int e) {
    int i = blockIdx.x * blockDim.x + threadIdx.x;
    if (i < e) {
        float ds = deg[src[i]], dd = deg[dst[i]];
        float is = ds > 0.f ? rsqrtf(fmaxf(ds, EPSV)) : 0.f;
        float id = dd > 0.f ? rsqrtf(fmaxf(dd, EPSV)) : 0.f;
        nrm[i] = is * ew[i] * id;
    }
}

// ------------------------------------------------------- BN stats (col sums)
// sums[0..DIM) = sum, sums[DIM..2*DIM) = sum of squares.
// FUSE: value = relu(in + bias)  (used for the post-conv BN).
template <int DIM, bool FUSE>
__global__ __launch_bounds__(256) void bn_stats_k(const float* __restrict__ in,
                                                  const float* __restrict__ bias,
                                                  float* __restrict__ sums, int n) {
    constexpr int RPI = 256 / DIM;        // rows per block-iteration
    int f    = threadIdx.x % DIM;
    int rsub = threadIdx.x / DIM;
    float b  = FUSE ? bias[f] : 0.f;
    float s = 0.f, s2 = 0.f;
    for (int r = blockIdx.x * RPI + rsub; r < n; r += gridDim.x * RPI) {
        float v = in[(size_t)r * DIM + f];
        if (FUSE) v = fmaxf(v + b, 0.f);
        s += v; s2 += v * v;
    }
    atomAdd(&sums[f], s);
    atomAdd(&sums[DIM + f], s2);
}

// --------------------------------------------------- BN fold: a = g*rstd etc
__global__ void bn_fold_k(const float* __restrict__ sums,
                          const float* __restrict__ gamma,
                          const float* __restrict__ beta,
                          float* __restrict__ a_out, float* __restrict__ c_out,
                          int dim, float invN) {
    int f = blockIdx.x * blockDim.x + threadIdx.x;
    if (f < dim) {
        float mean = sums[f] * invN;
        float var  = sums[dim + f] * invN - mean * mean;
        float a    = gamma[f] * rsqrtf(var + EPSV);
        a_out[f] = a;
        c_out[f] = beta[f] - mean * a;
    }
}

// ------------------------------------------------- fold diag(a) into W rows
__global__ void fold_w_k(const float* __restrict__ W, const float* __restrict__ a,
                         float* __restrict__ Wf, int K, int M) {
    int i = blockIdx.x * blockDim.x + threadIdx.x;
    if (i < K * M) Wf[i] = W[i] * a[i / M];
}

// ------------------------------------- d[j] = sum_f c[f]*W[f,j] (+ extra[j])
__global__ void fold_d_k(const float* __restrict__ W, const float* __restrict__ c,
                         const float* __restrict__ extra, float* __restrict__ d,
                         int K, int M) {
    int j = threadIdx.x;           // blockDim == M
    float s = extra ? extra[j] : 0.f;
    for (int f = 0; f < K; f++) s += c[f] * W[f * M + j];
    d[j] = s;
}

// ----------------------------------------------------------- tiled fp32 GEMM
// C[n, M] = op_in(A[n, K]) @ B[K, M] (+ outBias) (relu if RELU_OUT)
// op_in: FUSE_IN ? relu(A + preBias[k]) : A
template <int K, int M, bool FUSE_IN, bool RELU_OUT>
__global__ __launch_bounds__(256) void gemm_k(const float* __restrict__ A,
                                              const float* __restrict__ preBias,
                                              const float* __restrict__ B,
                                              const float* __restrict__ outBias,
                                              float* __restrict__ C, int n) {
    constexpr int BM = 64, BK = 16;
    constexpr int TM = 4;
    constexpr int TN = M / 16;                 // 8 (M=128) or 4 (M=64)
    constexpr int BVEC = (BK * M) / (256 * 4); // float4 loads/thread for B

    __shared__ float As[BM][BK + 1];
    __shared__ __align__(16) float Bs[BK][M];

    const int tid  = threadIdx.x;
    const int row0 = blockIdx.x * BM;
    const int tx   = tid % 16;
    const int ty   = tid / 16;

    float acc[TM][TN];
#pragma unroll
    for (int i = 0; i < TM; i++)
#pragma unroll
        for (int j = 0; j < TN; j++) acc[i][j] = 0.f;

    const int ar = tid / 4;          // 0..63
    const int ac = (tid % 4) * 4;    // 0,4,8,12

    for (int k0 = 0; k0 < K; k0 += BK) {
        // ---- stage A tile (with optional fused bias+relu on the K features)
        {
            int grow = row0 + ar;
            float4 av = make_float4(0.f, 0.f, 0.f, 0.f);
            if (grow < n) {
                av = *(const float4*)&A[(size_t)grow * K + k0 + ac];
                if (FUSE_IN) {
                    av.x = fmaxf(av.x + preBias[k0 + ac + 0], 0.f);
                    av.y = fmaxf(av.y + preBias[k0 + ac + 1], 0.f);
                    av.z = fmaxf(av.z + preBias[k0 + ac + 2], 0.f);
                    av.w = fmaxf(av.w + preBias[k0 + ac + 3], 0.f);
                }
            }
            As[ar][ac + 0] = av.x;
            As[ar][ac + 1] = av.y;
            As[ar][ac + 2] = av.z;
            As[ar][ac + 3] = av.w;
        }
        // ---- stage B tile
#pragma unroll
        for (int v = 0; v < BVEC; v++) {
            int idx = (tid + v * 256) * 4;     // float index into tile
            int kk  = idx / M;
            int j   = idx % M;
            *(float4*)&Bs[kk][j] = *(const float4*)&B[(size_t)(k0 + kk) * M + j];
        }
        __syncthreads();

#pragma unroll
        for (int kk = 0; kk < BK; kk++) {
            float a[TM], b[TN];
#pragma unroll
            for (int i = 0; i < TM; i++) a[i] = As[ty * TM + i][kk];
#pragma unroll
            for (int j = 0; j < TN; j += 4) {
                float4 bv = *(float4*)&Bs[kk][tx * TN + j];
                b[j + 0] = bv.x; b[j + 1] = bv.y; b[j + 2] = bv.z; b[j + 3] = bv.w;
            }
#pragma unroll
            for (int i = 0; i < TM; i++)
#pragma unroll
                for (int j = 0; j < TN; j++) acc[i][j] += a[i] * b[j];
        }
        __syncthreads();
    }

    // ---- epilogue
#pragma unroll
    for (int i = 0; i < TM; i++) {
        int grow = row0 + ty * TM + i;
        if (grow < n) {
#pragma unroll
            for (int j = 0; j < TN; j += 4) {
                float4 o;
                o.x = acc[i][j + 0]; o.y = acc[i][j + 1];
                o.z = acc[i][j + 2]; o.w = acc[i][j + 3];
                if (outBias) {
                    o.x += outBias[tx * TN + j + 0];
                    o.y += outBias[tx * TN + j + 1];
                    o.z += outBias[tx * TN + j + 2];
                    o.w += outBias[tx * TN + j + 3];
                }
                if (RELU_OUT) {
                    o.x = fmaxf(o.x, 0.f); o.y = fmaxf(o.y, 0.f);
                    o.z = fmaxf(o.z, 0.f); o.w = fmaxf(o.w, 0.f);
                }
                *(float4*)&C[(size_t)grow * M + tx * TN + j] = o;
            }
        }
    }
}

// -------------------------------------------------- edge aggregation (atomic)
// agg[dst] += norm[e] * t[src];  one wave per edge, 2 floats per lane (HD=128)
__global__ __launch_bounds__(256) void agg_k(const float* __restrict__ t,
                                             const int* __restrict__ src,
                                             const int* __restrict__ dst,
                                             const float* __restrict__ nrm,
                                             float* __restrict__ agg, int e) {
    int lane = threadIdx.x & 63;
    int wid  = (blockIdx.x * blockDim.x + threadIdx.x) >> 6;
    int nw   = (gridDim.x * blockDim.x) >> 6;
    for (int i = wid; i < e; i += nw) {
        int s = src[i], d = dst[i];
        float w = nrm[i];
        float2 v = *(const float2*)&t[(size_t)s * HD + lane * 2];
        atomAdd(&agg[(size_t)d * HD + lane * 2 + 0], w * v.x);
        atomAdd(&agg[(size_t)d * HD + lane * 2 + 1], w * v.y);
    }
}

// ============================================================== host driver
extern "C" void kernel_launch(void* const* d_in, const int* in_sizes, int n_in,
                              void* d_out, int out_size, void* d_ws, size_t ws_size,
                              hipStream_t stream) {
    const float* x        = (const float*)d_in[0];
    const int*   ei       = (const int*)d_in[1];   // [2, E] int32
    const float* ew       = (const float*)d_in[2];
    const float* bn_gamma = (const float*)d_in[3];
    const float* bn_beta  = (const float*)d_in[4];
    const float* W0       = (const float*)d_in[5];
    const float* b0       = (const float*)d_in[6];
    const float* W1       = (const float*)d_in[7];
    const float* b1       = (const float*)d_in[8];
    const float* W2       = (const float*)d_in[9];
    const float* b2       = (const float*)d_in[10];
    const float* pgamma   = (const float*)d_in[11];
    const float* pbeta    = (const float*)d_in[12];
    const float* pW       = (const float*)d_in[13];
    const float* pb       = (const float*)d_in[14];
    float* out = (float*)d_out;

    const int* srcp = ei;
    const int* dstp = ei + NEDGE;

    // ---- workspace carve (256B aligned)
    char*  base = (char*)d_ws;
    size_t off  = 0;
    auto carve = [&](size_t bytes) -> float* {
        float* p = (float*)(base + off);
        off = (off + bytes + 255) & ~(size_t)255;
        return p;
    };
    float* deg    = carve(NN * 4);
    float* nrm    = carve(NEDGE * 4);
    float* stats  = carve(2 * INDIM * 4);
    float* afold  = carve(INDIM * 4);
    float* cfold  = carve(INDIM * 4);
    float* W0f    = carve(INDIM * HD * 4);
    float* d0     = carve(HD * 4);
    float* stats2 = carve(2 * HD * 4);
    float* a2     = carve(HD * 4);
    float* c2     = carve(HD * 4);
    float* pWf    = carve(HD * OUTD * 4);
    float* dfin   = carve(OUTD * 4);
    float* tbuf   = carve((size_t)NN * HD * 4);
    float* aggb   = carve((size_t)NN * HD * 4);
    (void)ws_size;

    const int eBlocks = (NEDGE + 255) / 256;
    const int gemmGrid = (NN + 63) / 64;

    // ---- degree + edge norm
    hipMemsetAsync(deg, 0, NN * 4, stream);
    deg_k<<<eBlocks, 256, 0, stream>>>(dstp, ew, deg, NEDGE);
    norm_k<<<eBlocks, 256, 0, stream>>>(srcp, dstp, ew, deg, nrm, NEDGE);

    // ---- BN(x) stats + fold into W0
    hipMemsetAsync(stats, 0, 2 * INDIM * 4, stream);
    bn_stats_k<INDIM, false><<<512, 256, 0, stream>>>(x, nullptr, stats, NN);
    bn_fold_k<<<1, INDIM, 0, stream>>>(stats, bn_gamma, bn_beta, afold, cfold,
                                       INDIM, 1.f / NN);
    fold_w_k<<<(INDIM * HD + 255) / 256, 256, 0, stream>>>(W0, afold, W0f, INDIM, HD);
    fold_d_k<<<1, HD, 0, stream>>>(W0, cfold, nullptr, d0, INDIM, HD);

    // ---- layer 0: t = x @ W0f + d0 ; agg
    gemm_k<INDIM, HD, false, false><<<gemmGrid, 256, 0, stream>>>(
        x, nullptr, W0f, d0, tbuf, NN);
    hipMemsetAsync(aggb, 0, (size_t)NN * HD * 4, stream);
    agg_k<<<4096, 256, 0, stream>>>(tbuf, srcp, dstp, nrm, aggb, NEDGE);

    // ---- layer 1: t = relu(agg + b0) @ W1 ; agg
    gemm_k<HD, HD, true, false><<<gemmGrid, 256, 0, stream>>>(
        aggb, b0, W1, nullptr, tbuf, NN);
    hipMemsetAsync(aggb, 0, (size_t)NN * HD * 4, stream);
    agg_k<<<4096, 256, 0, stream>>>(tbuf, srcp, dstp, nrm, aggb, NEDGE);

    // ---- layer 2: t = relu(agg + b1) @ W2 ; agg
    gemm_k<HD, HD, true, false><<<gemmGrid, 256, 0, stream>>>(
        aggb, b1, W2, nullptr, tbuf, NN);
    hipMemsetAsync(aggb, 0, (size_t)NN * HD * 4, stream);
    agg_k<<<4096, 256, 0, stream>>>(tbuf, srcp, dstp, nrm, aggb, NEDGE);

    // ---- head: BN(relu(agg + b2)) -> Linear -> ReLU
    hipMemsetAsync(stats2, 0, 2 * HD * 4, stream);
    bn_stats_k<HD, true><<<512, 256, 0, stream>>>(aggb, b2, stats2, NN);
    bn_fold_k<<<1, HD, 0, stream>>>(stats2, pgamma, pbeta, a2, c2, HD, 1.f / NN);
    fold_w_k<<<(HD * OUTD + 255) / 256, 256, 0, stream>>>(pW, a2, pWf, HD, OUTD);
    fold_d_k<<<1, OUTD, 0, stream>>>(pW, c2, pb, dfin, HD, OUTD);

    gemm_k<HD, OUTD, true, true><<<gemmGrid, 256, 0, stream>>>(
        aggb, b2, pWf, dfin, out, NN);

    (void)n_in; (void)in_sizes; (void)out_size;
}

// Round 2
// 965.823 us; speedup vs baseline: 2.2891x; 2.2891x over previous
//
#include <hip/hip_runtime.h>

// GCN forward: BN(x) -> [GCNConv+ReLU] x3 -> BN -> Linear+ReLU
// N=100000 nodes, E=600000 edges, dims 256->128->128->128->64, all fp32.
//
// R2: replaced atomic scatter-add aggregation (600 MB of atomic write traffic
// per layer, 67% of runtime) with CSR-sorted gather aggregation: counting
// sort by dst (hist -> scan -> scatter), then one wave per node accumulates
// in registers and writes once.

constexpr int NN     = 100000;
constexpr int NEDGE  = 600000;
constexpr int INDIM  = 256;
constexpr int HD     = 128;   // hidden dim for all three conv layers
constexpr int OUTD   = 64;
#define EPSV 1e-5f

__device__ __forceinline__ void atomAdd(float* p, float v) {
    unsafeAtomicAdd(p, v);   // native global_atomic_add_f32 on gfx950
}

// ------------------------------------------------------------ degree kernel
__global__ __launch_bounds__(256) void deg_k(const int* __restrict__ dst,
                                             const float* __restrict__ ew,
                                             float* __restrict__ deg, int e) {
    int i = blockIdx.x * blockDim.x + threadIdx.x;
    if (i < e) atomAdd(&deg[dst[i]], ew[i]);
}

// -------------------------------------------------------------- norm kernel
__global__ __launch_bounds__(256) void norm_k(const int* __restrict__ src,
                                              const int* __restrict__ dst,
                                              const float* __restrict__ ew,
                                              const float* __restrict__ deg,
                                              float* __restrict__ nrm, int e) {
    int i = blockIdx.x * blockDim.x + threadIdx.x;
    if (i < e) {
        float ds = deg[src[i]], dd = deg[dst[i]];
        float is = ds > 0.f ? rsqrtf(fmaxf(ds, EPSV)) : 0.f;
        float id = dd > 0.f ? rsqrtf(fmaxf(dd, EPSV)) : 0.f;
        nrm[i] = is * ew[i] * id;
    }
}

// ------------------------------------------------------------- CSR building
__global__ __launch_bounds__(256) void hist_k(const int* __restrict__ dst,
                                              int* __restrict__ cnt, int e) {
    int i = blockIdx.x * blockDim.x + threadIdx.x;
    if (i < e) atomicAdd(&cnt[dst[i]], 1);
}

// per-block inclusive scan of cnt -> rowptr[i+1]; block totals -> bsum
__global__ __launch_bounds__(256) void scan1_k(const int* __restrict__ cnt,
                                               int* __restrict__ rowptr,
                                               int* __restrict__ bsum, int n) {
    __shared__ int s[256];
    int i = blockIdx.x * 256 + threadIdx.x;
    s[threadIdx.x] = (i < n) ? cnt[i] : 0;
    __syncthreads();
    for (int d = 1; d < 256; d <<= 1) {
        int t = (threadIdx.x >= d) ? s[threadIdx.x - d] : 0;
        __syncthreads();
        s[threadIdx.x] += t;
        __syncthreads();
    }
    if (i < n) rowptr[i + 1] = s[threadIdx.x];
    if (threadIdx.x == 255) bsum[blockIdx.x] = s[255];
}

// single-block inclusive scan of block sums (nb <= 512), in place
__global__ __launch_bounds__(512) void scan2_k(int* __restrict__ bsum, int nb) {
    __shared__ int s[512];
    s[threadIdx.x] = (threadIdx.x < (unsigned)nb) ? bsum[threadIdx.x] : 0;
    __syncthreads();
    for (int d = 1; d < 512; d <<= 1) {
        int t = (threadIdx.x >= d) ? s[threadIdx.x - d] : 0;
        __syncthreads();
        s[threadIdx.x] += t;
        __syncthreads();
    }
    if (threadIdx.x < (unsigned)nb) bsum[threadIdx.x] = s[threadIdx.x];
}

// add scanned block offsets; also rowptr[0] = 0 and copy rowptr -> cursor
__global__ __launch_bounds__(256) void scan3_k(int* __restrict__ rowptr,
                                               const int* __restrict__ bsum,
                                               int* __restrict__ cursor, int n) {
    int i = blockIdx.x * 256 + threadIdx.x;
    if (i == 0) { rowptr[0] = 0; cursor[0] = 0; }
    if (i < n) {
        int v = rowptr[i + 1];
        if (blockIdx.x > 0) v += bsum[blockIdx.x - 1];
        rowptr[i + 1] = v;
        if (i + 1 < n) cursor[i + 1] = v;
    }
}

// scatter edges into CSR order (order within a row nondeterministic; fp-sum
// reorder only perturbs rounding)
__global__ __launch_bounds__(256) void scatter_k(const int* __restrict__ src,
                                                 const int* __restrict__ dst,
                                                 const float* __restrict__ nrm,
                                                 int* __restrict__ cursor,
                                                 int* __restrict__ esrc,
                                                 float* __restrict__ enrm, int e) {
    int i = blockIdx.x * blockDim.x + threadIdx.x;
    if (i < e) {
        int p = atomicAdd(&cursor[dst[i]], 1);
        esrc[p] = src[i];
        enrm[p] = nrm[i];
    }
}

// ------------------------------------------------------- BN stats (col sums)
template <int DIM, bool FUSE>
__global__ __launch_bounds__(256) void bn_stats_k(const float* __restrict__ in,
                                                  const float* __restrict__ bias,
                                                  float* __restrict__ sums, int n) {
    constexpr int RPI = 256 / DIM;
    int f    = threadIdx.x % DIM;
    int rsub = threadIdx.x / DIM;
    float b  = FUSE ? bias[f] : 0.f;
    float s = 0.f, s2 = 0.f;
    for (int r = blockIdx.x * RPI + rsub; r < n; r += gridDim.x * RPI) {
        float v = in[(size_t)r * DIM + f];
        if (FUSE) v = fmaxf(v + b, 0.f);
        s += v; s2 += v * v;
    }
    atomAdd(&sums[f], s);
    atomAdd(&sums[DIM + f], s2);
}

__global__ void bn_fold_k(const float* __restrict__ sums,
                          const float* __restrict__ gamma,
                          const float* __restrict__ beta,
                          float* __restrict__ a_out, float* __restrict__ c_out,
                          int dim, float invN) {
    int f = blockIdx.x * blockDim.x + threadIdx.x;
    if (f < dim) {
        float mean = sums[f] * invN;
        float var  = sums[dim + f] * invN - mean * mean;
        float a    = gamma[f] * rsqrtf(var + EPSV);
        a_out[f] = a;
        c_out[f] = beta[f] - mean * a;
    }
}

__global__ void fold_w_k(const float* __restrict__ W, const float* __restrict__ a,
                         float* __restrict__ Wf, int K, int M) {
    int i = blockIdx.x * blockDim.x + threadIdx.x;
    if (i < K * M) Wf[i] = W[i] * a[i / M];
}

__global__ void fold_d_k(const float* __restrict__ W, const float* __restrict__ c,
                         const float* __restrict__ extra, float* __restrict__ d,
                         int K, int M) {
    int j = threadIdx.x;           // blockDim == M
    float s = extra ? extra[j] : 0.f;
    for (int f = 0; f < K; f++) s += c[f] * W[f * M + j];
    d[j] = s;
}

// ----------------------------------------------------------- tiled fp32 GEMM
template <int K, int M, bool FUSE_IN, bool RELU_OUT>
__global__ __launch_bounds__(256) void gemm_k(const float* __restrict__ A,
                                              const float* __restrict__ preBias,
                                              const float* __restrict__ B,
                                              const float* __restrict__ outBias,
                                              float* __restrict__ C, int n) {
    constexpr int BM = 64, BK = 16;
    constexpr int TM = 4;
    constexpr int TN = M / 16;
    constexpr int BVEC = (BK * M) / (256 * 4);

    __shared__ float As[BM][BK + 1];
    __shared__ __align__(16) float Bs[BK][M];

    const int tid  = threadIdx.x;
    const int row0 = blockIdx.x * BM;
    const int tx   = tid % 16;
    const int ty   = tid / 16;

    float acc[TM][TN];
#pragma unroll
    for (int i = 0; i < TM; i++)
#pragma unroll
        for (int j = 0; j < TN; j++) acc[i][j] = 0.f;

    const int ar = tid / 4;
    const int ac = (tid % 4) * 4;

    for (int k0 = 0; k0 < K; k0 += BK) {
        {
            int grow = row0 + ar;
            float4 av = make_float4(0.f, 0.f, 0.f, 0.f);
            if (grow < n) {
                av = *(const float4*)&A[(size_t)grow * K + k0 + ac];
                if (FUSE_IN) {
                    av.x = fmaxf(av.x + preBias[k0 + ac + 0], 0.f);
                    av.y = fmaxf(av.y + preBias[k0 + ac + 1], 0.f);
                    av.z = fmaxf(av.z + preBias[k0 + ac + 2], 0.f);
                    av.w = fmaxf(av.w + preBias[k0 + ac + 3], 0.f);
                }
            }
            As[ar][ac + 0] = av.x;
            As[ar][ac + 1] = av.y;
            As[ar][ac + 2] = av.z;
            As[ar][ac + 3] = av.w;
        }
#pragma unroll
        for (int v = 0; v < BVEC; v++) {
            int idx = (tid + v * 256) * 4;
            int kk  = idx / M;
            int j   = idx % M;
            *(float4*)&Bs[kk][j] = *(const float4*)&B[(size_t)(k0 + kk) * M + j];
        }
        __syncthreads();

#pragma unroll
        for (int kk = 0; kk < BK; kk++) {
            float a[TM], b[TN];
#pragma unroll
            for (int i = 0; i < TM; i++) a[i] = As[ty * TM + i][kk];
#pragma unroll
            for (int j = 0; j < TN; j += 4) {
                float4 bv = *(float4*)&Bs[kk][tx * TN + j];
                b[j + 0] = bv.x; b[j + 1] = bv.y; b[j + 2] = bv.z; b[j + 3] = bv.w;
            }
#pragma unroll
            for (int i = 0; i < TM; i++)
#pragma unroll
                for (int j = 0; j < TN; j++) acc[i][j] += a[i] * b[j];
        }
        __syncthreads();
    }

#pragma unroll
    for (int i = 0; i < TM; i++) {
        int grow = row0 + ty * TM + i;
        if (grow < n) {
#pragma unroll
            for (int j = 0; j < TN; j += 4) {
                float4 o;
                o.x = acc[i][j + 0]; o.y = acc[i][j + 1];
                o.z = acc[i][j + 2]; o.w = acc[i][j + 3];
                if (outBias) {
                    o.x += outBias[tx * TN + j + 0];
                    o.y += outBias[tx * TN + j + 1];
                    o.z += outBias[tx * TN + j + 2];
                    o.w += outBias[tx * TN + j + 3];
                }
                if (RELU_OUT) {
                    o.x = fmaxf(o.x, 0.f); o.y = fmaxf(o.y, 0.f);
                    o.z = fmaxf(o.z, 0.f); o.w = fmaxf(o.w, 0.f);
                }
                *(float4*)&C[(size_t)grow * M + tx * TN + j] = o;
            }
        }
    }
}

// -------------------------------------------------- CSR gather aggregation
// one wave per dst node; 2 floats/lane (HD=128); each output written once
__global__ __launch_bounds__(256) void agg_csr_k(const float* __restrict__ t,
                                                 const int* __restrict__ rowptr,
                                                 const int* __restrict__ esrc,
                                                 const float* __restrict__ enrm,
                                                 float* __restrict__ agg, int n) {
    int wid  = (blockIdx.x * blockDim.x + threadIdx.x) >> 6;
    int lane = threadIdx.x & 63;
    if (wid >= n) return;
    int beg = rowptr[wid], end = rowptr[wid + 1];
    float ax = 0.f, ay = 0.f;
    for (int i = beg; i < end; i++) {
        int   s = esrc[i];
        float w = enrm[i];
        float2 v = *(const float2*)&t[(size_t)s * HD + lane * 2];
        ax += w * v.x;
        ay += w * v.y;
    }
    *(float2*)&agg[(size_t)wid * HD + lane * 2] = make_float2(ax, ay);
}

// ============================================================== host driver
extern "C" void kernel_launch(void* const* d_in, const int* in_sizes, int n_in,
                              void* d_out, int out_size, void* d_ws, size_t ws_size,
                              hipStream_t stream) {
    const float* x        = (const float*)d_in[0];
    const int*   ei       = (const int*)d_in[1];   // [2, E] int32
    const float* ew       = (const float*)d_in[2];
    const float* bn_gamma = (const float*)d_in[3];
    const float* bn_beta  = (const float*)d_in[4];
    const float* W0       = (const float*)d_in[5];
    const float* b0       = (const float*)d_in[6];
    const float* W1       = (const float*)d_in[7];
    const float* b1       = (const float*)d_in[8];
    const float* W2       = (const float*)d_in[9];
    const float* b2       = (const float*)d_in[10];
    const float* pgamma   = (const float*)d_in[11];
    const float* pbeta    = (const float*)d_in[12];
    const float* pW       = (const float*)d_in[13];
    const float* pb       = (const float*)d_in[14];
    float* out = (float*)d_out;

    const int* srcp = ei;
    const int* dstp = ei + NEDGE;

    char*  base = (char*)d_ws;
    size_t off  = 0;
    auto carve = [&](size_t bytes) -> void* {
        void* p = (void*)(base + off);
        off = (off + bytes + 255) & ~(size_t)255;
        return p;
    };
    float* deg    = (float*)carve(NN * 4);
    float* nrm    = (float*)carve(NEDGE * 4);
    int*   cnt    = (int*)carve(NN * 4);
    int*   rowptr = (int*)carve((NN + 1) * 4);
    int*   cursor = (int*)carve(NN * 4);
    int*   bsum   = (int*)carve(512 * 4);
    int*   esrc   = (int*)carve(NEDGE * 4);
    float* enrm   = (float*)carve(NEDGE * 4);
    float* stats  = (float*)carve(2 * INDIM * 4);
    float* afold  = (float*)carve(INDIM * 4);
    float* cfold  = (float*)carve(INDIM * 4);
    float* W0f    = (float*)carve(INDIM * HD * 4);
    float* d0     = (float*)carve(HD * 4);
    float* stats2 = (float*)carve(2 * HD * 4);
    float* a2     = (float*)carve(HD * 4);
    float* c2     = (float*)carve(HD * 4);
    float* pWf    = (float*)carve(HD * OUTD * 4);
    float* dfin   = (float*)carve(OUTD * 4);
    float* tbuf   = (float*)carve((size_t)NN * HD * 4);
    float* aggb   = (float*)carve((size_t)NN * HD * 4);
    (void)ws_size;

    const int eBlocks  = (NEDGE + 255) / 256;
    const int nBlocks  = (NN + 255) / 256;       // 391 <= 512
    const int gemmGrid = (NN + 63) / 64;
    const int aggGrid  = (NN * 64 + 255) / 256;  // one wave per node

    // ---- degree + edge norm
    hipMemsetAsync(deg, 0, NN * 4, stream);
    deg_k<<<eBlocks, 256, 0, stream>>>(dstp, ew, deg, NEDGE);
    norm_k<<<eBlocks, 256, 0, stream>>>(srcp, dstp, ew, deg, nrm, NEDGE);

    // ---- CSR build (counting sort by dst)
    hipMemsetAsync(cnt, 0, NN * 4, stream);
    hist_k<<<eBlocks, 256, 0, stream>>>(dstp, cnt, NEDGE);
    scan1_k<<<nBlocks, 256, 0, stream>>>(cnt, rowptr, bsum, NN);
    scan2_k<<<1, 512, 0, stream>>>(bsum, nBlocks);
    scan3_k<<<nBlocks, 256, 0, stream>>>(rowptr, bsum, cursor, NN);
    scatter_k<<<eBlocks, 256, 0, stream>>>(srcp, dstp, nrm, cursor, esrc, enrm, NEDGE);

    // ---- BN(x) stats + fold into W0
    hipMemsetAsync(stats, 0, 2 * INDIM * 4, stream);
    bn_stats_k<INDIM, false><<<512, 256, 0, stream>>>(x, nullptr, stats, NN);
    bn_fold_k<<<1, INDIM, 0, stream>>>(stats, bn_gamma, bn_beta, afold, cfold,
                                       INDIM, 1.f / NN);
    fold_w_k<<<(INDIM * HD + 255) / 256, 256, 0, stream>>>(W0, afold, W0f, INDIM, HD);
    fold_d_k<<<1, HD, 0, stream>>>(W0, cfold, nullptr, d0, INDIM, HD);

    // ---- layer 0
    gemm_k<INDIM, HD, false, false><<<gemmGrid, 256, 0, stream>>>(
        x, nullptr, W0f, d0, tbuf, NN);
    agg_csr_k<<<aggGrid, 256, 0, stream>>>(tbuf, rowptr, esrc, enrm, aggb, NN);

    // ---- layer 1
    gemm_k<HD, HD, true, false><<<gemmGrid, 256, 0, stream>>>(
        aggb, b0, W1, nullptr, tbuf, NN);
    agg_csr_k<<<aggGrid, 256, 0, stream>>>(tbuf, rowptr, esrc, enrm, aggb, NN);

    // ---- layer 2
    gemm_k<HD, HD, true, false><<<gemmGrid, 256, 0, stream>>>(
        aggb, b1, W2, nullptr, tbuf, NN);
    agg_csr_k<<<aggGrid, 256, 0, stream>>>(tbuf, rowptr, esrc, enrm, aggb, NN);

    // ---- head: BN(relu(agg + b2)) -> Linear -> ReLU
    hipMemsetAsync(stats2, 0, 2 * HD * 4, stream);
    bn_stats_k<HD, true><<<512, 256, 0, stream>>>(aggb, b2, stats2, NN);
    bn_fold_k<<<1, HD, 0, stream>>>(stats2, pgamma, pbeta, a2, c2, HD, 1.f / NN);
    fold_w_k<<<(HD * OUTD + 255) / 256, 256, 0, stream>>>(pW, a2, pWf, HD, OUTD);
    fold_d_k<<<1, OUTD, 0, stream>>>(pW, c2, pb, dfin, HD, OUTD);

    gemm_k<HD, OUTD, true, true><<<gemmGrid, 256, 0, stream>>>(
        aggb, b2, pWf, dfin, out, NN);

    (void)n_in; (void)in_sizes; (void)out_size;
}

// Round 3
// 817.864 us; speedup vs baseline: 2.7032x; 1.1809x over previous
//
#include <hip/hip_runtime.h>

// GCN forward: BN(x) -> [GCNConv+ReLU] x3 -> BN -> Linear+ReLU
// N=100000 nodes, E=600000 edges, dims 256->128->128->128->64, fp32 in/out.
//
// R3: GEMMs moved to bf16 MFMA (mfma_f32_16x16x32_bf16, fp32 accum); all
// inter-layer buffers bf16 (halves aggregation gather/write traffic).
// Weights pre-transposed+bf16 so A and B frags are contiguous ds_read_b128.

constexpr int NN     = 100000;
constexpr int NEDGE  = 600000;
constexpr int INDIM  = 256;
constexpr int HD     = 128;
constexpr int OUTD   = 64;
#define EPSV 1e-5f

typedef __bf16 bf16x8 __attribute__((ext_vector_type(8)));
typedef float  f32x4  __attribute__((ext_vector_type(4)));

__device__ __forceinline__ float bf2f(unsigned short u) {
    unsigned int v = ((unsigned int)u) << 16;
    return __builtin_bit_cast(float, v);
}
__device__ __forceinline__ unsigned short f2bf(float f) {
    __bf16 h = (__bf16)f;                       // RNE convert
    return __builtin_bit_cast(unsigned short, h);
}
__device__ __forceinline__ void atomAdd(float* p, float v) {
    unsafeAtomicAdd(p, v);
}

// ------------------------------------------------------------ degree + norm
__global__ __launch_bounds__(256) void deg_k(const int* __restrict__ dst,
                                             const float* __restrict__ ew,
                                             float* __restrict__ deg, int e) {
    int i = blockIdx.x * blockDim.x + threadIdx.x;
    if (i < e) atomAdd(&deg[dst[i]], ew[i]);
}

__global__ __launch_bounds__(256) void norm_k(const int* __restrict__ src,
                                              const int* __restrict__ dst,
                                              const float* __restrict__ ew,
                                              const float* __restrict__ deg,
                                              float* __restrict__ nrm, int e) {
    int i = blockIdx.x * blockDim.x + threadIdx.x;
    if (i < e) {
        float ds = deg[src[i]], dd = deg[dst[i]];
        float is = ds > 0.f ? rsqrtf(fmaxf(ds, EPSV)) : 0.f;
        float id = dd > 0.f ? rsqrtf(fmaxf(dd, EPSV)) : 0.f;
        nrm[i] = is * ew[i] * id;
    }
}

// ------------------------------------------------------------- CSR building
__global__ __launch_bounds__(256) void hist_k(const int* __restrict__ dst,
                                              int* __restrict__ cnt, int e) {
    int i = blockIdx.x * blockDim.x + threadIdx.x;
    if (i < e) atomicAdd(&cnt[dst[i]], 1);
}

__global__ __launch_bounds__(256) void scan1_k(const int* __restrict__ cnt,
                                               int* __restrict__ rowptr,
                                               int* __restrict__ bsum, int n) {
    __shared__ int s[256];
    int i = blockIdx.x * 256 + threadIdx.x;
    s[threadIdx.x] = (i < n) ? cnt[i] : 0;
    __syncthreads();
    for (int d = 1; d < 256; d <<= 1) {
        int t = (threadIdx.x >= d) ? s[threadIdx.x - d] : 0;
        __syncthreads();
        s[threadIdx.x] += t;
        __syncthreads();
    }
    if (i < n) rowptr[i + 1] = s[threadIdx.x];
    if (threadIdx.x == 255) bsum[blockIdx.x] = s[255];
}

__global__ __launch_bounds__(512) void scan2_k(int* __restrict__ bsum, int nb) {
    __shared__ int s[512];
    s[threadIdx.x] = (threadIdx.x < (unsigned)nb) ? bsum[threadIdx.x] : 0;
    __syncthreads();
    for (int d = 1; d < 512; d <<= 1) {
        int t = (threadIdx.x >= d) ? s[threadIdx.x - d] : 0;
        __syncthreads();
        s[threadIdx.x] += t;
        __syncthreads();
    }
    if (threadIdx.x < (unsigned)nb) bsum[threadIdx.x] = s[threadIdx.x];
}

__global__ __launch_bounds__(256) void scan3_k(int* __restrict__ rowptr,
                                               const int* __restrict__ bsum,
                                               int* __restrict__ cursor, int n) {
    int i = blockIdx.x * 256 + threadIdx.x;
    if (i == 0) { rowptr[0] = 0; cursor[0] = 0; }
    if (i < n) {
        int v = rowptr[i + 1];
        if (blockIdx.x > 0) v += bsum[blockIdx.x - 1];
        rowptr[i + 1] = v;
        if (i + 1 < n) cursor[i + 1] = v;
    }
}

__global__ __launch_bounds__(256) void scatter_k(const int* __restrict__ src,
                                                 const int* __restrict__ dst,
                                                 const float* __restrict__ nrm,
                                                 int* __restrict__ cursor,
                                                 int* __restrict__ esrc,
                                                 float* __restrict__ enrm, int e) {
    int i = blockIdx.x * blockDim.x + threadIdx.x;
    if (i < e) {
        int p = atomicAdd(&cursor[dst[i]], 1);
        esrc[p] = src[i];
        enrm[p] = nrm[i];
    }
}

// ------------------------------------------------------------ BN statistics
// fp32 input version (for x, DIM=256)
template <int DIM>
__global__ __launch_bounds__(256) void bn_stats_k(const float* __restrict__ in,
                                                  float* __restrict__ sums, int n) {
    constexpr int RPI = 256 / DIM;
    int f    = threadIdx.x % DIM;
    int rsub = threadIdx.x / DIM;
    float s = 0.f, s2 = 0.f;
    for (int r = blockIdx.x * RPI + rsub; r < n; r += gridDim.x * RPI) {
        float v = in[(size_t)r * DIM + f];
        s += v; s2 += v * v;
    }
    atomAdd(&sums[f], s);
    atomAdd(&sums[DIM + f], s2);
}

// bf16 input version with fused relu(v + bias) (head BN over relu(agg+b2))
__global__ __launch_bounds__(256) void bn_stats16_k(const unsigned short* __restrict__ in,
                                                    const float* __restrict__ bias,
                                                    float* __restrict__ sums, int n) {
    int f    = threadIdx.x & 127;   // DIM = 128
    int rsub = threadIdx.x >> 7;
    float b  = bias[f];
    float s = 0.f, s2 = 0.f;
    for (int r = blockIdx.x * 2 + rsub; r < n; r += gridDim.x * 2) {
        float v = fmaxf(bf2f(in[(size_t)r * 128 + f]) + b, 0.f);
        s += v; s2 += v * v;
    }
    atomAdd(&sums[f], s);
    atomAdd(&sums[128 + f], s2);
}

__global__ void bn_fold_k(const float* __restrict__ sums,
                          const float* __restrict__ gamma,
                          const float* __restrict__ beta,
                          float* __restrict__ a_out, float* __restrict__ c_out,
                          int dim, float invN) {
    int f = blockIdx.x * blockDim.x + threadIdx.x;
    if (f < dim) {
        float mean = sums[f] * invN;
        float var  = sums[dim + f] * invN - mean * mean;
        float a    = gamma[f] * rsqrtf(var + EPSV);
        a_out[f] = a;
        c_out[f] = beta[f] - mean * a;
    }
}

// W[K][M] fp32 (optionally row-scaled by a[k]) -> Wt[M][K] bf16
__global__ void fold_wt_k(const float* __restrict__ W, const float* __restrict__ a,
                          unsigned short* __restrict__ Wt, int K_, int M_) {
    int i = blockIdx.x * blockDim.x + threadIdx.x;
    if (i < K_ * M_) {
        int k = i / M_, j = i % M_;
        float v = W[i] * (a ? a[k] : 1.f);
        Wt[(size_t)j * K_ + k] = f2bf(v);
    }
}

// d[j] = sum_f c[f]*W[f,j] (+ extra[j])   (fp32)
__global__ void fold_d_k(const float* __restrict__ W, const float* __restrict__ c,
                         const float* __restrict__ extra, float* __restrict__ d,
                         int K_, int M_) {
    int j = threadIdx.x;           // blockDim == M_
    float s = extra ? extra[j] : 0.f;
    for (int f = 0; f < K_; f++) s += c[f] * W[f * M_ + j];
    d[j] = s;
}

// ------------------------------------------------------------ MFMA bf16 GEMM
// C[n,M] = op(A[n,K]) @ Bt^T  (+outBias) (relu?)   Bt is [M][K] bf16.
// op: FUSE_IN ? relu(A + preBias[k]) : A.  A is fp32 if A_FP32 else bf16.
// Block: 256 thr (4 waves), tile 128 x M. Wave = 64x64 (M=128) or 32x64 (M=64).
template <int K, int M, bool A_FP32, bool FUSE_IN, bool RELU_OUT, bool OUT_BF16>
__global__ __launch_bounds__(256) void mgemm_k(const void* __restrict__ Araw,
                                               const float* __restrict__ preBias,
                                               const unsigned short* __restrict__ Bt,
                                               const float* __restrict__ outBias,
                                               void* __restrict__ Craw, int n) {
    constexpr int BK  = 64;
    constexpr int LDA = BK + 8;                 // 72 ushorts = 144 B row stride
    __shared__ unsigned short As[128 * LDA];
    __shared__ unsigned short Bs[M * LDA];

    const int tid  = threadIdx.x;
    const int wave = tid >> 6, lane = tid & 63;
    const int quad = lane >> 4, mrow = lane & 15;
    const int row0 = blockIdx.x * 128;

    constexpr int RT = (M == 128) ? 4 : 2;      // 16-row tiles per wave
    constexpr int CT = 4;                       // 16-col tiles per wave
    const int rowbase = (M == 128) ? ((wave >> 1) * 64) : (wave * 32);
    const int colbase = (M == 128) ? ((wave & 1) * 64) : 0;

    f32x4 acc[RT][CT];
#pragma unroll
    for (int i = 0; i < RT; i++)
#pragma unroll
        for (int j = 0; j < CT; j++) acc[i][j] = (f32x4){0.f, 0.f, 0.f, 0.f};

    for (int k0 = 0; k0 < K; k0 += BK) {
        // ---- stage A tile: 128 rows x 64 cols, 8 bf16 per thread per pass
#pragma unroll
        for (int p = 0; p < 4; p++) {
            int c   = p * 256 + tid;            // chunk id, 8 bf16 each
            int r   = c >> 3;
            int c8  = (c & 7) * 8;
            int grow = row0 + r;
            if (A_FP32 || FUSE_IN) {
                float vf[8];
                if (A_FP32) {
                    const float* Af = (const float*)Araw;
                    float4 v0 = make_float4(0.f, 0.f, 0.f, 0.f), v1 = v0;
                    if (grow < n) {
                        v0 = *(const float4*)&Af[(size_t)grow * K + k0 + c8];
                        v1 = *(const float4*)&Af[(size_t)grow * K + k0 + c8 + 4];
                    }
                    vf[0] = v0.x; vf[1] = v0.y; vf[2] = v0.z; vf[3] = v0.w;
                    vf[4] = v1.x; vf[5] = v1.y; vf[6] = v1.z; vf[7] = v1.w;
                } else {
                    const unsigned short* Ab = (const unsigned short*)Araw;
                    uint4 u = make_uint4(0, 0, 0, 0);
                    if (grow < n) u = *(const uint4*)&Ab[(size_t)grow * K + k0 + c8];
                    vf[0] = bf2f((unsigned short)(u.x & 0xffff));
                    vf[1] = bf2f((unsigned short)(u.x >> 16));
                    vf[2] = bf2f((unsigned short)(u.y & 0xffff));
                    vf[3] = bf2f((unsigned short)(u.y >> 16));
                    vf[4] = bf2f((unsigned short)(u.z & 0xffff));
                    vf[5] = bf2f((unsigned short)(u.z >> 16));
                    vf[6] = bf2f((unsigned short)(u.w & 0xffff));
                    vf[7] = bf2f((unsigned short)(u.w >> 16));
                }
                if (FUSE_IN) {
#pragma unroll
                    for (int j = 0; j < 8; j++)
                        vf[j] = fmaxf(vf[j] + preBias[k0 + c8 + j], 0.f);
                }
                unsigned int w0 = (unsigned int)f2bf(vf[0]) | ((unsigned int)f2bf(vf[1]) << 16);
                unsigned int w1 = (unsigned int)f2bf(vf[2]) | ((unsigned int)f2bf(vf[3]) << 16);
                unsigned int w2 = (unsigned int)f2bf(vf[4]) | ((unsigned int)f2bf(vf[5]) << 16);
                unsigned int w3 = (unsigned int)f2bf(vf[6]) | ((unsigned int)f2bf(vf[7]) << 16);
                *(uint4*)&As[r * LDA + c8] = make_uint4(w0, w1, w2, w3);
            } else {
                const unsigned short* Ab = (const unsigned short*)Araw;
                uint4 u = make_uint4(0, 0, 0, 0);
                if (grow < n) u = *(const uint4*)&Ab[(size_t)grow * K + k0 + c8];
                *(uint4*)&As[r * LDA + c8] = u;
            }
        }
        // ---- stage B tile: M rows x 64 cols
#pragma unroll
        for (int p = 0; p < M / 32; p++) {
            int c  = p * 256 + tid;
            int r  = c >> 3;
            int c8 = (c & 7) * 8;
            *(uint4*)&Bs[r * LDA + c8] = *(const uint4*)&Bt[(size_t)r * K + k0 + c8];
        }
        __syncthreads();

        // ---- MFMA over this K-chunk (2 steps of 32)
#pragma unroll
        for (int ks = 0; ks < BK; ks += 32) {
            bf16x8 af[RT], bfr[CT];
#pragma unroll
            for (int i = 0; i < RT; i++)
                af[i] = *(const bf16x8*)&As[(rowbase + i * 16 + mrow) * LDA + ks + quad * 8];
#pragma unroll
            for (int j = 0; j < CT; j++)
                bfr[j] = *(const bf16x8*)&Bs[(colbase + j * 16 + mrow) * LDA + ks + quad * 8];
#pragma unroll
            for (int i = 0; i < RT; i++)
#pragma unroll
                for (int j = 0; j < CT; j++)
                    acc[i][j] = __builtin_amdgcn_mfma_f32_16x16x32_bf16(
                        af[i], bfr[j], acc[i][j], 0, 0, 0);
        }
        __syncthreads();
    }

    // ---- epilogue: D[row=quad*4+r][col=lane&15] per 16x16 tile (m89 layout)
#pragma unroll
    for (int i = 0; i < RT; i++) {
#pragma unroll
        for (int r = 0; r < 4; r++) {
            int row = row0 + rowbase + i * 16 + quad * 4 + r;
            if (row < n) {
#pragma unroll
                for (int j = 0; j < CT; j++) {
                    int col = colbase + j * 16 + mrow;
                    float v = acc[i][j][r];
                    if (outBias) v += outBias[col];
                    if (RELU_OUT) v = fmaxf(v, 0.f);
                    if (OUT_BF16)
                        ((unsigned short*)Craw)[(size_t)row * M + col] = f2bf(v);
                    else
                        ((float*)Craw)[(size_t)row * M + col] = v;
                }
            }
        }
    }
}

// -------------------------------------------------- CSR gather aggregation
// one wave per dst node; bf16 in, fp32 accumulate, bf16 out; 2 cols/lane
__global__ __launch_bounds__(256) void agg_csr16_k(const unsigned short* __restrict__ t,
                                                   const int* __restrict__ rowptr,
                                                   const int* __restrict__ esrc,
                                                   const float* __restrict__ enrm,
                                                   unsigned short* __restrict__ agg,
                                                   int n) {
    int wid  = (blockIdx.x * blockDim.x + threadIdx.x) >> 6;
    int lane = threadIdx.x & 63;
    if (wid >= n) return;
    int beg = rowptr[wid], end = rowptr[wid + 1];
    float ax = 0.f, ay = 0.f;
    for (int i = beg; i < end; i++) {
        int   s = esrc[i];
        float w = enrm[i];
        unsigned int v = *(const unsigned int*)&t[(size_t)s * HD + lane * 2];
        ax += w * bf2f((unsigned short)(v & 0xffff));
        ay += w * bf2f((unsigned short)(v >> 16));
    }
    unsigned int o = (unsigned int)f2bf(ax) | ((unsigned int)f2bf(ay) << 16);
    *(unsigned int*)&agg[(size_t)wid * HD + lane * 2] = o;
}

// ============================================================== host driver
extern "C" void kernel_launch(void* const* d_in, const int* in_sizes, int n_in,
                              void* d_out, int out_size, void* d_ws, size_t ws_size,
                              hipStream_t stream) {
    const float* x        = (const float*)d_in[0];
    const int*   ei       = (const int*)d_in[1];   // [2, E] int32
    const float* ew       = (const float*)d_in[2];
    const float* bn_gamma = (const float*)d_in[3];
    const float* bn_beta  = (const float*)d_in[4];
    const float* W0       = (const float*)d_in[5];
    const float* b0       = (const float*)d_in[6];
    const float* W1       = (const float*)d_in[7];
    const float* b1       = (const float*)d_in[8];
    const float* W2       = (const float*)d_in[9];
    const float* b2       = (const float*)d_in[10];
    const float* pgamma   = (const float*)d_in[11];
    const float* pbeta    = (const float*)d_in[12];
    const float* pW       = (const float*)d_in[13];
    const float* pb       = (const float*)d_in[14];
    float* out = (float*)d_out;

    const int* srcp = ei;
    const int* dstp = ei + NEDGE;

    char*  base = (char*)d_ws;
    size_t off  = 0;
    auto carve = [&](size_t bytes) -> void* {
        void* p = (void*)(base + off);
        off = (off + bytes + 255) & ~(size_t)255;
        return p;
    };
    float*          deg    = (float*)carve(NN * 4);
    float*          nrm    = (float*)carve(NEDGE * 4);
    int*            cnt    = (int*)carve(NN * 4);
    int*            rowptr = (int*)carve((NN + 1) * 4);
    int*            cursor = (int*)carve(NN * 4);
    int*            bsum   = (int*)carve(512 * 4);
    int*            esrc   = (int*)carve(NEDGE * 4);
    float*          enrm   = (float*)carve(NEDGE * 4);
    float*          stats  = (float*)carve(2 * INDIM * 4);
    float*          afold  = (float*)carve(INDIM * 4);
    float*          cfold  = (float*)carve(INDIM * 4);
    float*          d0     = (float*)carve(HD * 4);
    float*          stats2 = (float*)carve(2 * HD * 4);
    float*          a2     = (float*)carve(HD * 4);
    float*          c2     = (float*)carve(HD * 4);
    float*          dfin   = (float*)carve(OUTD * 4);
    unsigned short* W0t    = (unsigned short*)carve((size_t)INDIM * HD * 2);
    unsigned short* W1t    = (unsigned short*)carve((size_t)HD * HD * 2);
    unsigned short* W2t    = (unsigned short*)carve((size_t)HD * HD * 2);
    unsigned short* pWt    = (unsigned short*)carve((size_t)HD * OUTD * 2);
    unsigned short* tbuf   = (unsigned short*)carve((size_t)NN * HD * 2);
    unsigned short* aggb   = (unsigned short*)carve((size_t)NN * HD * 2);
    (void)ws_size;

    const int eBlocks  = (NEDGE + 255) / 256;
    const int nBlocks  = (NN + 255) / 256;        // 391 <= 512
    const int gemmGrid = (NN + 127) / 128;        // 782
    const int aggGrid  = (NN * 64 + 255) / 256;   // one wave per node

    // ---- degree + edge norm
    hipMemsetAsync(deg, 0, NN * 4, stream);
    deg_k<<<eBlocks, 256, 0, stream>>>(dstp, ew, deg, NEDGE);
    norm_k<<<eBlocks, 256, 0, stream>>>(srcp, dstp, ew, deg, nrm, NEDGE);

    // ---- CSR build (counting sort by dst)
    hipMemsetAsync(cnt, 0, NN * 4, stream);
    hist_k<<<eBlocks, 256, 0, stream>>>(dstp, cnt, NEDGE);
    scan1_k<<<nBlocks, 256, 0, stream>>>(cnt, rowptr, bsum, NN);
    scan2_k<<<1, 512, 0, stream>>>(bsum, nBlocks);
    scan3_k<<<nBlocks, 256, 0, stream>>>(rowptr, bsum, cursor, NN);
    scatter_k<<<eBlocks, 256, 0, stream>>>(srcp, dstp, nrm, cursor, esrc, enrm, NEDGE);

    // ---- BN(x) stats; fold scale into W0 (transposed bf16), shift into d0
    hipMemsetAsync(stats, 0, 2 * INDIM * 4, stream);
    bn_stats_k<INDIM><<<512, 256, 0, stream>>>(x, stats, NN);
    bn_fold_k<<<1, INDIM, 0, stream>>>(stats, bn_gamma, bn_beta, afold, cfold,
                                       INDIM, 1.f / NN);
    fold_wt_k<<<(INDIM * HD + 255) / 256, 256, 0, stream>>>(W0, afold, W0t, INDIM, HD);
    fold_d_k<<<1, HD, 0, stream>>>(W0, cfold, nullptr, d0, INDIM, HD);
    // plain transpose+cast for W1, W2
    fold_wt_k<<<(HD * HD + 255) / 256, 256, 0, stream>>>(W1, nullptr, W1t, HD, HD);
    fold_wt_k<<<(HD * HD + 255) / 256, 256, 0, stream>>>(W2, nullptr, W2t, HD, HD);

    // ---- layer 0: t = x @ W0f + d0 (fp32 A, bf16 out) ; agg
    mgemm_k<INDIM, HD, true, false, false, true><<<gemmGrid, 256, 0, stream>>>(
        x, nullptr, W0t, d0, tbuf, NN);
    agg_csr16_k<<<aggGrid, 256, 0, stream>>>(tbuf, rowptr, esrc, enrm, aggb, NN);

    // ---- layer 1: t = relu(agg + b0) @ W1 ; agg
    mgemm_k<HD, HD, false, true, false, true><<<gemmGrid, 256, 0, stream>>>(
        aggb, b0, W1t, nullptr, tbuf, NN);
    agg_csr16_k<<<aggGrid, 256, 0, stream>>>(tbuf, rowptr, esrc, enrm, aggb, NN);

    // ---- layer 2: t = relu(agg + b1) @ W2 ; agg
    mgemm_k<HD, HD, false, true, false, true><<<gemmGrid, 256, 0, stream>>>(
        aggb, b1, W2t, nullptr, tbuf, NN);
    agg_csr16_k<<<aggGrid, 256, 0, stream>>>(tbuf, rowptr, esrc, enrm, aggb, NN);

    // ---- head: BN(relu(agg + b2)) -> Linear -> ReLU
    hipMemsetAsync(stats2, 0, 2 * HD * 4, stream);
    bn_stats16_k<<<512, 256, 0, stream>>>(aggb, b2, stats2, NN);
    bn_fold_k<<<1, HD, 0, stream>>>(stats2, pgamma, pbeta, a2, c2, HD, 1.f / NN);
    fold_wt_k<<<(HD * OUTD + 255) / 256, 256, 0, stream>>>(pW, a2, pWt, HD, OUTD);
    fold_d_k<<<1, OUTD, 0, stream>>>(pW, c2, pb, dfin, HD, OUTD);

    mgemm_k<HD, OUTD, false, true, true, false><<<gemmGrid, 256, 0, stream>>>(
        aggb, b2, pWt, dfin, out, NN);

    (void)n_in; (void)in_sizes; (void)out_size;
}

// Round 4
// 667.435 us; speedup vs baseline: 3.3125x; 1.2254x over previous
//
#include <hip/hip_runtime.h>

// GCN forward: BN(x) -> [GCNConv+ReLU] x3 -> BN -> Linear+ReLU
// N=100000 nodes, E=600000 edges, dims 256->128->128->128->64, fp32 in/out.
//
// R4: vectorized BN-stats (float4/bf16x8 + LDS block reduce; was 109 us of
// scalar latency-bound loads); bias+relu folded into agg epilogue so all
// GEMM A-inputs are plain bf16 (staging = pure uint4 copy); agg gather
// unrolled x4 for MLP; deg+hist fused; norm computed inline in scatter.

constexpr int NN     = 100000;
constexpr int NEDGE  = 600000;
constexpr int INDIM  = 256;
constexpr int HD     = 128;
constexpr int OUTD   = 64;
#define EPSV 1e-5f

typedef __bf16 bf16x8 __attribute__((ext_vector_type(8)));
typedef float  f32x4  __attribute__((ext_vector_type(4)));

__device__ __forceinline__ float bf2f(unsigned short u) {
    unsigned int v = ((unsigned int)u) << 16;
    return __builtin_bit_cast(float, v);
}
__device__ __forceinline__ unsigned short f2bf(float f) {
    __bf16 h = (__bf16)f;                       // RNE convert
    return __builtin_bit_cast(unsigned short, h);
}
__device__ __forceinline__ void atomAdd(float* p, float v) {
    unsafeAtomicAdd(p, v);
}

// --------------------------------------------- degree + edge-count (fused)
__global__ __launch_bounds__(256) void deghist_k(const int* __restrict__ dst,
                                                 const float* __restrict__ ew,
                                                 float* __restrict__ deg,
                                                 int* __restrict__ cnt, int e) {
    int i = blockIdx.x * blockDim.x + threadIdx.x;
    if (i < e) {
        int d = dst[i];
        atomAdd(&deg[d], ew[i]);
        atomicAdd(&cnt[d], 1);
    }
}

// ------------------------------------------------------------- CSR scans
__global__ __launch_bounds__(256) void scan1_k(const int* __restrict__ cnt,
                                               int* __restrict__ rowptr,
                                               int* __restrict__ bsum, int n) {
    __shared__ int s[256];
    int i = blockIdx.x * 256 + threadIdx.x;
    s[threadIdx.x] = (i < n) ? cnt[i] : 0;
    __syncthreads();
    for (int d = 1; d < 256; d <<= 1) {
        int t = (threadIdx.x >= d) ? s[threadIdx.x - d] : 0;
        __syncthreads();
        s[threadIdx.x] += t;
        __syncthreads();
    }
    if (i < n) rowptr[i + 1] = s[threadIdx.x];
    if (threadIdx.x == 255) bsum[blockIdx.x] = s[255];
}

__global__ __launch_bounds__(512) void scan2_k(int* __restrict__ bsum, int nb) {
    __shared__ int s[512];
    s[threadIdx.x] = (threadIdx.x < (unsigned)nb) ? bsum[threadIdx.x] : 0;
    __syncthreads();
    for (int d = 1; d < 512; d <<= 1) {
        int t = (threadIdx.x >= d) ? s[threadIdx.x - d] : 0;
        __syncthreads();
        s[threadIdx.x] += t;
        __syncthreads();
    }
    if (threadIdx.x < (unsigned)nb) bsum[threadIdx.x] = s[threadIdx.x];
}

__global__ __launch_bounds__(256) void scan3_k(int* __restrict__ rowptr,
                                               const int* __restrict__ bsum,
                                               int* __restrict__ cursor, int n) {
    int i = blockIdx.x * 256 + threadIdx.x;
    if (i == 0) { rowptr[0] = 0; cursor[0] = 0; }
    if (i < n) {
        int v = rowptr[i + 1];
        if (blockIdx.x > 0) v += bsum[blockIdx.x - 1];
        rowptr[i + 1] = v;
        if (i + 1 < n) cursor[i + 1] = v;
    }
}

// ---------------------- scatter into CSR order, norm computed inline
__global__ __launch_bounds__(256) void scatter_k(const int* __restrict__ src,
                                                 const int* __restrict__ dst,
                                                 const float* __restrict__ ew,
                                                 const float* __restrict__ deg,
                                                 int* __restrict__ cursor,
                                                 int* __restrict__ esrc,
                                                 float* __restrict__ enrm, int e) {
    int i = blockIdx.x * blockDim.x + threadIdx.x;
    if (i < e) {
        int s = src[i], d = dst[i];
        float ds = deg[s], dd = deg[d];
        float is = ds > 0.f ? rsqrtf(fmaxf(ds, EPSV)) : 0.f;
        float id = dd > 0.f ? rsqrtf(fmaxf(dd, EPSV)) : 0.f;
        float nm = is * ew[i] * id;
        int p = atomicAdd(&cursor[d], 1);
        esrc[p] = s;
        enrm[p] = nm;
    }
}

// ------------------------------------------- BN stats over x (fp32, DIM=256)
// float4 loads, per-block LDS reduce, also emits bf16 copy of x.
__global__ __launch_bounds__(256) void bn_stats_x_k(const float* __restrict__ in,
                                                    float* __restrict__ sums,
                                                    unsigned short* __restrict__ xb,
                                                    int n) {
    const int tid = threadIdx.x;
    const int cg  = tid & 63;       // float4 chunk within row (256 = 64*4)
    const int rs  = tid >> 6;       // 0..3
    float s0 = 0.f, s1 = 0.f, s2 = 0.f, s3 = 0.f;
    float q0 = 0.f, q1 = 0.f, q2 = 0.f, q3 = 0.f;
    for (int r = blockIdx.x * 4 + rs; r < n; r += gridDim.x * 4) {
        float4 v = *(const float4*)&in[(size_t)r * INDIM + cg * 4];
        s0 += v.x; s1 += v.y; s2 += v.z; s3 += v.w;
        q0 += v.x * v.x; q1 += v.y * v.y; q2 += v.z * v.z; q3 += v.w * v.w;
        unsigned int w0 = (unsigned int)f2bf(v.x) | ((unsigned int)f2bf(v.y) << 16);
        unsigned int w1 = (unsigned int)f2bf(v.z) | ((unsigned int)f2bf(v.w) << 16);
        *(uint2*)&xb[(size_t)r * INDIM + cg * 4] = make_uint2(w0, w1);
    }
    __shared__ float red[256 * 8];
    red[tid * 8 + 0] = s0; red[tid * 8 + 1] = s1;
    red[tid * 8 + 2] = s2; red[tid * 8 + 3] = s3;
    red[tid * 8 + 4] = q0; red[tid * 8 + 5] = q1;
    red[tid * 8 + 6] = q2; red[tid * 8 + 7] = q3;
    __syncthreads();
    // feature f = tid; chunk = f>>2, elem j = f&3; sum over rs = 0..3
    int cgr = tid >> 2, j = tid & 3;
    float a = 0.f, b = 0.f;
#pragma unroll
    for (int r2 = 0; r2 < 4; r2++) {
        a += red[(r2 * 64 + cgr) * 8 + j];
        b += red[(r2 * 64 + cgr) * 8 + 4 + j];
    }
    atomAdd(&sums[tid], a);
    atomAdd(&sums[INDIM + tid], b);
}

// --------------------------------- BN stats over bf16 activations (DIM=128)
__global__ __launch_bounds__(256) void bn_stats16_k(const unsigned short* __restrict__ in,
                                                    float* __restrict__ sums, int n) {
    const int tid = threadIdx.x;
    const int cg  = tid & 15;       // 8-elem chunk within row (128 = 16*8)
    const int rs  = tid >> 4;       // 0..15
    float s[8], q[8];
#pragma unroll
    for (int j = 0; j < 8; j++) { s[j] = 0.f; q[j] = 0.f; }
    for (int r = blockIdx.x * 16 + rs; r < n; r += gridDim.x * 16) {
        uint4 u = *(const uint4*)&in[(size_t)r * HD + cg * 8];
        float v[8];
        v[0] = bf2f((unsigned short)(u.x & 0xffff)); v[1] = bf2f((unsigned short)(u.x >> 16));
        v[2] = bf2f((unsigned short)(u.y & 0xffff)); v[3] = bf2f((unsigned short)(u.y >> 16));
        v[4] = bf2f((unsigned short)(u.z & 0xffff)); v[5] = bf2f((unsigned short)(u.z >> 16));
        v[6] = bf2f((unsigned short)(u.w & 0xffff)); v[7] = bf2f((unsigned short)(u.w >> 16));
#pragma unroll
        for (int j = 0; j < 8; j++) { s[j] += v[j]; q[j] += v[j] * v[j]; }
    }
    __shared__ float red[256 * 16];
#pragma unroll
    for (int j = 0; j < 8; j++) {
        red[tid * 16 + j]     = s[j];
        red[tid * 16 + 8 + j] = q[j];
    }
    __syncthreads();
    if (tid < HD) {
        int cgr = tid >> 3, j = tid & 7;
        float a = 0.f, b = 0.f;
#pragma unroll
        for (int r2 = 0; r2 < 16; r2++) {
            a += red[(r2 * 16 + cgr) * 16 + j];
            b += red[(r2 * 16 + cgr) * 16 + 8 + j];
        }
        atomAdd(&sums[tid], a);
        atomAdd(&sums[HD + tid], b);
    }
}

__global__ void bn_fold_k(const float* __restrict__ sums,
                          const float* __restrict__ gamma,
                          const float* __restrict__ beta,
                          float* __restrict__ a_out, float* __restrict__ c_out,
                          int dim, float invN) {
    int f = blockIdx.x * blockDim.x + threadIdx.x;
    if (f < dim) {
        float mean = sums[f] * invN;
        float var  = sums[dim + f] * invN - mean * mean;
        float a    = gamma[f] * rsqrtf(var + EPSV);
        a_out[f] = a;
        c_out[f] = beta[f] - mean * a;
    }
}

// W[K][M] fp32 (optionally row-scaled by a[k]) -> Wt[M][K] bf16
__global__ void fold_wt_k(const float* __restrict__ W, const float* __restrict__ a,
                          unsigned short* __restrict__ Wt, int K_, int M_) {
    int i = blockIdx.x * blockDim.x + threadIdx.x;
    if (i < K_ * M_) {
        int k = i / M_, j = i % M_;
        float v = W[i] * (a ? a[k] : 1.f);
        Wt[(size_t)j * K_ + k] = f2bf(v);
    }
}

// d[j] = sum_f c[f]*W[f,j] (+ extra[j])   (fp32)
__global__ void fold_d_k(const float* __restrict__ W, const float* __restrict__ c,
                         const float* __restrict__ extra, float* __restrict__ d,
                         int K_, int M_) {
    int j = threadIdx.x;           // blockDim == M_
    float s = extra ? extra[j] : 0.f;
    for (int f = 0; f < K_; f++) s += c[f] * W[f * M_ + j];
    d[j] = s;
}

// ------------------------------------------------------------ MFMA bf16 GEMM
// C[n,M] = A[n,K] @ Bt^T (+outBias) (relu?); A bf16, Bt is [M][K] bf16.
// Block: 256 thr (4 waves), tile 128 x M.
template <int K, int M, bool RELU_OUT, bool OUT_BF16>
__global__ __launch_bounds__(256) void mgemm_k(const unsigned short* __restrict__ A,
                                               const unsigned short* __restrict__ Bt,
                                               const float* __restrict__ outBias,
                                               void* __restrict__ Craw, int n) {
    constexpr int BK  = 64;
    constexpr int LDA = BK + 8;                 // 72 ushorts = 144 B row stride
    __shared__ unsigned short As[128 * LDA];
    __shared__ unsigned short Bs[M * LDA];

    const int tid  = threadIdx.x;
    const int wave = tid >> 6, lane = tid & 63;
    const int quad = lane >> 4, mrow = lane & 15;
    const int row0 = blockIdx.x * 128;

    constexpr int RT = (M == 128) ? 4 : 2;
    constexpr int CT = 4;
    const int rowbase = (M == 128) ? ((wave >> 1) * 64) : (wave * 32);
    const int colbase = (M == 128) ? ((wave & 1) * 64) : 0;

    f32x4 acc[RT][CT];
#pragma unroll
    for (int i = 0; i < RT; i++)
#pragma unroll
        for (int j = 0; j < CT; j++) acc[i][j] = (f32x4){0.f, 0.f, 0.f, 0.f};

    for (int k0 = 0; k0 < K; k0 += BK) {
        // ---- stage A tile: 128 rows x 64 cols bf16, pure uint4 copy
#pragma unroll
        for (int p = 0; p < 4; p++) {
            int c   = p * 256 + tid;
            int r   = c >> 3;
            int c8  = (c & 7) * 8;
            int grow = row0 + r;
            uint4 u = make_uint4(0, 0, 0, 0);
            if (grow < n) u = *(const uint4*)&A[(size_t)grow * K + k0 + c8];
            *(uint4*)&As[r * LDA + c8] = u;
        }
        // ---- stage B tile: M rows x 64 cols
#pragma unroll
        for (int p = 0; p < M / 32; p++) {
            int c  = p * 256 + tid;
            int r  = c >> 3;
            int c8 = (c & 7) * 8;
            *(uint4*)&Bs[r * LDA + c8] = *(const uint4*)&Bt[(size_t)r * K + k0 + c8];
        }
        __syncthreads();

#pragma unroll
        for (int ks = 0; ks < BK; ks += 32) {
            bf16x8 af[RT], bfr[CT];
#pragma unroll
            for (int i = 0; i < RT; i++)
                af[i] = *(const bf16x8*)&As[(rowbase + i * 16 + mrow) * LDA + ks + quad * 8];
#pragma unroll
            for (int j = 0; j < CT; j++)
                bfr[j] = *(const bf16x8*)&Bs[(colbase + j * 16 + mrow) * LDA + ks + quad * 8];
#pragma unroll
            for (int i = 0; i < RT; i++)
#pragma unroll
                for (int j = 0; j < CT; j++)
                    acc[i][j] = __builtin_amdgcn_mfma_f32_16x16x32_bf16(
                        af[i], bfr[j], acc[i][j], 0, 0, 0);
        }
        __syncthreads();
    }

    // ---- epilogue: D[row=quad*4+r][col=lane&15] per 16x16 tile
#pragma unroll
    for (int i = 0; i < RT; i++) {
#pragma unroll
        for (int r = 0; r < 4; r++) {
            int row = row0 + rowbase + i * 16 + quad * 4 + r;
            if (row < n) {
#pragma unroll
                for (int j = 0; j < CT; j++) {
                    int col = colbase + j * 16 + mrow;
                    float v = acc[i][j][r];
                    if (outBias) v += outBias[col];
                    if (RELU_OUT) v = fmaxf(v, 0.f);
                    if (OUT_BF16)
                        ((unsigned short*)Craw)[(size_t)row * M + col] = f2bf(v);
                    else
                        ((float*)Craw)[(size_t)row * M + col] = v;
                }
            }
        }
    }
}

// -------------------------------------------------- CSR gather aggregation
// one wave per dst node; bf16 gather, fp32 accumulate, epilogue relu(v+bias)
// written once as bf16. Unrolled x4 for memory-level parallelism.
__global__ __launch_bounds__(256) void agg_csr16_k(const unsigned short* __restrict__ t,
                                                   const int* __restrict__ rowptr,
                                                   const int* __restrict__ esrc,
                                                   const float* __restrict__ enrm,
                                                   const float* __restrict__ bias,
                                                   unsigned short* __restrict__ agg,
                                                   int n) {
    int wid  = (blockIdx.x * blockDim.x + threadIdx.x) >> 6;
    int lane = threadIdx.x & 63;
    if (wid >= n) return;
    int beg = rowptr[wid], end = rowptr[wid + 1];
    float ax0 = 0.f, ay0 = 0.f, ax1 = 0.f, ay1 = 0.f;
    float ax2 = 0.f, ay2 = 0.f, ax3 = 0.f, ay3 = 0.f;
    int i = beg;
    for (; i + 4 <= end; i += 4) {
        int   s0 = esrc[i],     s1 = esrc[i + 1], s2 = esrc[i + 2], s3 = esrc[i + 3];
        float w0 = enrm[i],     w1 = enrm[i + 1], w2 = enrm[i + 2], w3 = enrm[i + 3];
        unsigned int v0 = *(const unsigned int*)&t[(size_t)s0 * HD + lane * 2];
        unsigned int v1 = *(const unsigned int*)&t[(size_t)s1 * HD + lane * 2];
        unsigned int v2 = *(const unsigned int*)&t[(size_t)s2 * HD + lane * 2];
        unsigned int v3 = *(const unsigned int*)&t[(size_t)s3 * HD + lane * 2];
        ax0 += w0 * bf2f((unsigned short)(v0 & 0xffff)); ay0 += w0 * bf2f((unsigned short)(v0 >> 16));
        ax1 += w1 * bf2f((unsigned short)(v1 & 0xffff)); ay1 += w1 * bf2f((unsigned short)(v1 >> 16));
        ax2 += w2 * bf2f((unsigned short)(v2 & 0xffff)); ay2 += w2 * bf2f((unsigned short)(v2 >> 16));
        ax3 += w3 * bf2f((unsigned short)(v3 & 0xffff)); ay3 += w3 * bf2f((unsigned short)(v3 >> 16));
    }
    for (; i < end; i++) {
        int   s = esrc[i];
        float w = enrm[i];
        unsigned int v = *(const unsigned int*)&t[(size_t)s * HD + lane * 2];
        ax0 += w * bf2f((unsigned short)(v & 0xffff));
        ay0 += w * bf2f((unsigned short)(v >> 16));
    }
    float ax = (ax0 + ax1) + (ax2 + ax3) + bias[lane * 2];
    float ay = (ay0 + ay1) + (ay2 + ay3) + bias[lane * 2 + 1];
    ax = fmaxf(ax, 0.f);
    ay = fmaxf(ay, 0.f);
    unsigned int o = (unsigned int)f2bf(ax) | ((unsigned int)f2bf(ay) << 16);
    *(unsigned int*)&agg[(size_t)wid * HD + lane * 2] = o;
}

// ============================================================== host driver
extern "C" void kernel_launch(void* const* d_in, const int* in_sizes, int n_in,
                              void* d_out, int out_size, void* d_ws, size_t ws_size,
                              hipStream_t stream) {
    const float* x        = (const float*)d_in[0];
    const int*   ei       = (const int*)d_in[1];   // [2, E] int32
    const float* ew       = (const float*)d_in[2];
    const float* bn_gamma = (const float*)d_in[3];
    const float* bn_beta  = (const float*)d_in[4];
    const float* W0       = (const float*)d_in[5];
    const float* b0       = (const float*)d_in[6];
    const float* W1       = (const float*)d_in[7];
    const float* b1       = (const float*)d_in[8];
    const float* W2       = (const float*)d_in[9];
    const float* b2       = (const float*)d_in[10];
    const float* pgamma   = (const float*)d_in[11];
    const float* pbeta    = (const float*)d_in[12];
    const float* pW       = (const float*)d_in[13];
    const float* pb       = (const float*)d_in[14];
    float* out = (float*)d_out;

    const int* srcp = ei;
    const int* dstp = ei + NEDGE;

    char*  base = (char*)d_ws;
    size_t off  = 0;
    auto carve = [&](size_t bytes) -> void* {
        void* p = (void*)(base + off);
        off = (off + bytes + 255) & ~(size_t)255;
        return p;
    };
    float*          deg    = (float*)carve(NN * 4);
    int*            cnt    = (int*)carve(NN * 4);
    int*            rowptr = (int*)carve((NN + 1) * 4);
    int*            cursor = (int*)carve(NN * 4);
    int*            bsum   = (int*)carve(512 * 4);
    int*            esrc   = (int*)carve(NEDGE * 4);
    float*          enrm   = (float*)carve(NEDGE * 4);
    float*          stats  = (float*)carve(2 * INDIM * 4);
    float*          afold  = (float*)carve(INDIM * 4);
    float*          cfold  = (float*)carve(INDIM * 4);
    float*          d0     = (float*)carve(HD * 4);
    float*          stats2 = (float*)carve(2 * HD * 4);
    float*          a2     = (float*)carve(HD * 4);
    float*          c2     = (float*)carve(HD * 4);
    float*          dfin   = (float*)carve(OUTD * 4);
    unsigned short* W0t    = (unsigned short*)carve((size_t)INDIM * HD * 2);
    unsigned short* W1t    = (unsigned short*)carve((size_t)HD * HD * 2);
    unsigned short* W2t    = (unsigned short*)carve((size_t)HD * HD * 2);
    unsigned short* pWt    = (unsigned short*)carve((size_t)HD * OUTD * 2);
    unsigned short* xb     = (unsigned short*)carve((size_t)NN * INDIM * 2);
    unsigned short* tbuf   = (unsigned short*)carve((size_t)NN * HD * 2);
    unsigned short* aggb   = (unsigned short*)carve((size_t)NN * HD * 2);
    (void)ws_size;

    const int eBlocks  = (NEDGE + 255) / 256;
    const int nBlocks  = (NN + 255) / 256;        // 391 <= 512
    const int gemmGrid = (NN + 127) / 128;        // 782
    const int aggGrid  = (NN * 64 + 255) / 256;   // one wave per node

    // ---- degree + histogram (fused), CSR build, scatter w/ inline norm
    hipMemsetAsync(deg, 0, NN * 4, stream);
    hipMemsetAsync(cnt, 0, NN * 4, stream);
    deghist_k<<<eBlocks, 256, 0, stream>>>(dstp, ew, deg, cnt, NEDGE);
    scan1_k<<<nBlocks, 256, 0, stream>>>(cnt, rowptr, bsum, NN);
    scan2_k<<<1, 512, 0, stream>>>(bsum, nBlocks);
    scan3_k<<<nBlocks, 256, 0, stream>>>(rowptr, bsum, cursor, NN);
    scatter_k<<<eBlocks, 256, 0, stream>>>(srcp, dstp, ew, deg, cursor, esrc, enrm, NEDGE);

    // ---- BN(x) stats (+ bf16 copy of x); fold into W0 (transposed bf16)
    hipMemsetAsync(stats, 0, 2 * INDIM * 4, stream);
    bn_stats_x_k<<<2048, 256, 0, stream>>>(x, stats, xb, NN);
    bn_fold_k<<<1, INDIM, 0, stream>>>(stats, bn_gamma, bn_beta, afold, cfold,
                                       INDIM, 1.f / NN);
    fold_wt_k<<<(INDIM * HD + 255) / 256, 256, 0, stream>>>(W0, afold, W0t, INDIM, HD);
    fold_d_k<<<1, HD, 0, stream>>>(W0, cfold, nullptr, d0, INDIM, HD);
    fold_wt_k<<<(HD * HD + 255) / 256, 256, 0, stream>>>(W1, nullptr, W1t, HD, HD);
    fold_wt_k<<<(HD * HD + 255) / 256, 256, 0, stream>>>(W2, nullptr, W2t, HD, HD);

    // ---- layer 0: t = xb @ W0t^T + d0 ; agg -> relu(agg + b0)
    mgemm_k<INDIM, HD, false, true><<<gemmGrid, 256, 0, stream>>>(
        xb, W0t, d0, tbuf, NN);
    agg_csr16_k<<<aggGrid, 256, 0, stream>>>(tbuf, rowptr, esrc, enrm, b0, aggb, NN);

    // ---- layer 1
    mgemm_k<HD, HD, false, true><<<gemmGrid, 256, 0, stream>>>(
        aggb, W1t, nullptr, tbuf, NN);
    agg_csr16_k<<<aggGrid, 256, 0, stream>>>(tbuf, rowptr, esrc, enrm, b1, aggb, NN);

    // ---- layer 2
    mgemm_k<HD, HD, false, true><<<gemmGrid, 256, 0, stream>>>(
        aggb, W2t, nullptr, tbuf, NN);
    agg_csr16_k<<<aggGrid, 256, 0, stream>>>(tbuf, rowptr, esrc, enrm, b2, aggb, NN);

    // ---- head: BN(aggb) -> Linear -> ReLU   (aggb already = relu(agg+b2))
    hipMemsetAsync(stats2, 0, 2 * HD * 4, stream);
    bn_stats16_k<<<512, 256, 0, stream>>>(aggb, stats2, NN);
    bn_fold_k<<<1, HD, 0, stream>>>(stats2, pgamma, pbeta, a2, c2, HD, 1.f / NN);
    fold_wt_k<<<(HD * OUTD + 255) / 256, 256, 0, stream>>>(pW, a2, pWt, HD, OUTD);
    fold_d_k<<<1, OUTD, 0, stream>>>(pW, c2, pb, dfin, HD, OUTD);

    mgemm_k<HD, OUTD, true, false><<<gemmGrid, 256, 0, stream>>>(
        aggb, pWt, dfin, out, NN);

    (void)n_in; (void)in_sizes; (void)out_size;
}

// Round 5
// 529.420 us; speedup vs baseline: 4.1760x; 1.2607x over previous
//
#include <hip/hip_runtime.h>

// GCN forward: BN(x) -> [GCNConv+ReLU] x3 -> BN -> Linear+ReLU
// N=100000 nodes, E=600000 edges, dims 256->128->128->128->64, fp32 in/out.
//
// R5: bn_stats_x 4x row-unrolled (4 loads in flight; was 1 -> latency-bound
// at 1.26 TB/s); weight-prep kernels merged (bn_fold+fold_wt x3+fold_d -> 1,
// head's 3 -> 1); memsets merged; agg gather gets predicated 4-wide tail
// (avg degree 6 made the serial remainder dominant).

constexpr int NN     = 100000;
constexpr int NEDGE  = 600000;
constexpr int INDIM  = 256;
constexpr int HD     = 128;
constexpr int OUTD   = 64;
#define EPSV 1e-5f

typedef __bf16 bf16x8 __attribute__((ext_vector_type(8)));
typedef float  f32x4  __attribute__((ext_vector_type(4)));

__device__ __forceinline__ float bf2f(unsigned short u) {
    unsigned int v = ((unsigned int)u) << 16;
    return __builtin_bit_cast(float, v);
}
__device__ __forceinline__ unsigned short f2bf(float f) {
    __bf16 h = (__bf16)f;                       // RNE convert
    return __builtin_bit_cast(unsigned short, h);
}
__device__ __forceinline__ void atomAdd(float* p, float v) {
    unsafeAtomicAdd(p, v);
}

// --------------------------------------------- degree + edge-count (fused)
__global__ __launch_bounds__(256) void deghist_k(const int* __restrict__ dst,
                                                 const float* __restrict__ ew,
                                                 float* __restrict__ deg,
                                                 int* __restrict__ cnt, int e) {
    int i = blockIdx.x * blockDim.x + threadIdx.x;
    if (i < e) {
        int d = dst[i];
        atomAdd(&deg[d], ew[i]);
        atomicAdd(&cnt[d], 1);
    }
}

// ------------------------------------------------------------- CSR scans
__global__ __launch_bounds__(256) void scan1_k(const int* __restrict__ cnt,
                                               int* __restrict__ rowptr,
                                               int* __restrict__ bsum, int n) {
    __shared__ int s[256];
    int i = blockIdx.x * 256 + threadIdx.x;
    s[threadIdx.x] = (i < n) ? cnt[i] : 0;
    __syncthreads();
    for (int d = 1; d < 256; d <<= 1) {
        int t = (threadIdx.x >= d) ? s[threadIdx.x - d] : 0;
        __syncthreads();
        s[threadIdx.x] += t;
        __syncthreads();
    }
    if (i < n) rowptr[i + 1] = s[threadIdx.x];
    if (threadIdx.x == 255) bsum[blockIdx.x] = s[255];
}

__global__ __launch_bounds__(512) void scan2_k(int* __restrict__ bsum, int nb) {
    __shared__ int s[512];
    s[threadIdx.x] = (threadIdx.x < (unsigned)nb) ? bsum[threadIdx.x] : 0;
    __syncthreads();
    for (int d = 1; d < 512; d <<= 1) {
        int t = (threadIdx.x >= d) ? s[threadIdx.x - d] : 0;
        __syncthreads();
        s[threadIdx.x] += t;
        __syncthreads();
    }
    if (threadIdx.x < (unsigned)nb) bsum[threadIdx.x] = s[threadIdx.x];
}

__global__ __launch_bounds__(256) void scan3_k(int* __restrict__ rowptr,
                                               const int* __restrict__ bsum,
                                               int* __restrict__ cursor, int n) {
    int i = blockIdx.x * 256 + threadIdx.x;
    if (i == 0) { rowptr[0] = 0; cursor[0] = 0; }
    if (i < n) {
        int v = rowptr[i + 1];
        if (blockIdx.x > 0) v += bsum[blockIdx.x - 1];
        rowptr[i + 1] = v;
        if (i + 1 < n) cursor[i + 1] = v;
    }
}

// ---------------------- scatter into CSR order, norm computed inline
__global__ __launch_bounds__(256) void scatter_k(const int* __restrict__ src,
                                                 const int* __restrict__ dst,
                                                 const float* __restrict__ ew,
                                                 const float* __restrict__ deg,
                                                 int* __restrict__ cursor,
                                                 int* __restrict__ esrc,
                                                 float* __restrict__ enrm, int e) {
    int i = blockIdx.x * blockDim.x + threadIdx.x;
    if (i < e) {
        int s = src[i], d = dst[i];
        float ds = deg[s], dd = deg[d];
        float is = ds > 0.f ? rsqrtf(fmaxf(ds, EPSV)) : 0.f;
        float id = dd > 0.f ? rsqrtf(fmaxf(dd, EPSV)) : 0.f;
        float nm = is * ew[i] * id;
        int p = atomicAdd(&cursor[d], 1);
        esrc[p] = s;
        enrm[p] = nm;
    }
}

// ------------------------------------------- BN stats over x (fp32, DIM=256)
// 4x row-unrolled: 4 independent float4 loads in flight per thread.
// Also emits bf16 copy of x.
__global__ __launch_bounds__(256) void bn_stats_x_k(const float* __restrict__ in,
                                                    float* __restrict__ sums,
                                                    unsigned short* __restrict__ xb,
                                                    int n) {
    const int tid = threadIdx.x;
    const int cg  = tid & 63;       // float4 chunk within row (256 = 64*4)
    const int rs  = tid >> 6;       // 0..3
    float s0 = 0.f, s1 = 0.f, s2 = 0.f, s3 = 0.f;
    float q0 = 0.f, q1 = 0.f, q2 = 0.f, q3 = 0.f;
    for (int r0 = blockIdx.x * 16; r0 < n; r0 += gridDim.x * 16) {
        // n % 16 == 0, so all 16 rows of the group are valid
        float4 v[4];
#pragma unroll
        for (int j = 0; j < 4; j++)
            v[j] = *(const float4*)&in[(size_t)(r0 + rs + j * 4) * INDIM + cg * 4];
#pragma unroll
        for (int j = 0; j < 4; j++) {
            s0 += v[j].x; s1 += v[j].y; s2 += v[j].z; s3 += v[j].w;
            q0 += v[j].x * v[j].x; q1 += v[j].y * v[j].y;
            q2 += v[j].z * v[j].z; q3 += v[j].w * v[j].w;
            unsigned int w0 = (unsigned int)f2bf(v[j].x) | ((unsigned int)f2bf(v[j].y) << 16);
            unsigned int w1 = (unsigned int)f2bf(v[j].z) | ((unsigned int)f2bf(v[j].w) << 16);
            *(uint2*)&xb[(size_t)(r0 + rs + j * 4) * INDIM + cg * 4] = make_uint2(w0, w1);
        }
    }
    __shared__ float red[256 * 8];
    red[tid * 8 + 0] = s0; red[tid * 8 + 1] = s1;
    red[tid * 8 + 2] = s2; red[tid * 8 + 3] = s3;
    red[tid * 8 + 4] = q0; red[tid * 8 + 5] = q1;
    red[tid * 8 + 6] = q2; red[tid * 8 + 7] = q3;
    __syncthreads();
    int cgr = tid >> 2, j = tid & 3;
    float a = 0.f, b = 0.f;
#pragma unroll
    for (int r2 = 0; r2 < 4; r2++) {
        a += red[(r2 * 64 + cgr) * 8 + j];
        b += red[(r2 * 64 + cgr) * 8 + 4 + j];
    }
    atomAdd(&sums[tid], a);
    atomAdd(&sums[INDIM + tid], b);
}

// --------------------------------- BN stats over bf16 activations (DIM=128)
__global__ __launch_bounds__(256) void bn_stats16_k(const unsigned short* __restrict__ in,
                                                    float* __restrict__ sums, int n) {
    const int tid = threadIdx.x;
    const int cg  = tid & 15;       // 8-elem chunk within row (128 = 16*8)
    const int rs  = tid >> 4;       // 0..15
    float s[8], q[8];
#pragma unroll
    for (int j = 0; j < 8; j++) { s[j] = 0.f; q[j] = 0.f; }
    for (int r = blockIdx.x * 16 + rs; r < n; r += gridDim.x * 16) {
        uint4 u = *(const uint4*)&in[(size_t)r * HD + cg * 8];
        float v[8];
        v[0] = bf2f((unsigned short)(u.x & 0xffff)); v[1] = bf2f((unsigned short)(u.x >> 16));
        v[2] = bf2f((unsigned short)(u.y & 0xffff)); v[3] = bf2f((unsigned short)(u.y >> 16));
        v[4] = bf2f((unsigned short)(u.z & 0xffff)); v[5] = bf2f((unsigned short)(u.z >> 16));
        v[6] = bf2f((unsigned short)(u.w & 0xffff)); v[7] = bf2f((unsigned short)(u.w >> 16));
#pragma unroll
        for (int j = 0; j < 8; j++) { s[j] += v[j]; q[j] += v[j] * v[j]; }
    }
    __shared__ float red[256 * 16];
#pragma unroll
    for (int j = 0; j < 8; j++) {
        red[tid * 16 + j]     = s[j];
        red[tid * 16 + 8 + j] = q[j];
    }
    __syncthreads();
    if (tid < HD) {
        int cgr = tid >> 3, j = tid & 7;
        float a = 0.f, b = 0.f;
#pragma unroll
        for (int r2 = 0; r2 < 16; r2++) {
            a += red[(r2 * 16 + cgr) * 16 + j];
            b += red[(r2 * 16 + cgr) * 16 + 8 + j];
        }
        atomAdd(&sums[tid], a);
        atomAdd(&sums[HD + tid], b);
    }
}

// ------------------------------------------ combined weight prep, layer 0-2
// Each block recomputes the BN fold (256 features) locally, then does its
// slice of W0t (scaled), W1t, W2t (plain transpose+cast), or d0.
// grid = 257 blocks x 256 threads.
__global__ __launch_bounds__(256) void wprep1_k(const float* __restrict__ stats,
                                                const float* __restrict__ gamma,
                                                const float* __restrict__ beta,
                                                const float* __restrict__ W0,
                                                const float* __restrict__ W1,
                                                const float* __restrict__ W2,
                                                unsigned short* __restrict__ W0t,
                                                unsigned short* __restrict__ W1t,
                                                unsigned short* __restrict__ W2t,
                                                float* __restrict__ d0, float invN) {
    __shared__ float sA[INDIM], sC[INDIM];
    int f = threadIdx.x;
    {
        float mean = stats[f] * invN;
        float var  = stats[INDIM + f] * invN - mean * mean;
        float a    = gamma[f] * rsqrtf(var + EPSV);
        sA[f] = a;
        sC[f] = beta[f] - mean * a;
    }
    __syncthreads();
    int b = blockIdx.x, tid = threadIdx.x;
    if (b < 128) {                 // W0: 256x128, scale row k by sA[k]
        int i = b * 256 + tid, k = i >> 7, j = i & 127;
        W0t[(size_t)j * INDIM + k] = f2bf(W0[i] * sA[k]);
    } else if (b < 192) {          // W1: 128x128
        int i = (b - 128) * 256 + tid, k = i >> 7, j = i & 127;
        W1t[(size_t)j * HD + k] = f2bf(W1[i]);
    } else if (b < 256) {          // W2: 128x128
        int i = (b - 192) * 256 + tid, k = i >> 7, j = i & 127;
        W2t[(size_t)j * HD + k] = f2bf(W2[i]);
    } else {                       // d0[j] = sum_f sC[f]*W0[f,j]
        if (tid < HD) {
            float s = 0.f;
            for (int ff = 0; ff < INDIM; ff++) s += sC[ff] * W0[ff * HD + tid];
            d0[tid] = s;
        }
    }
}

// ------------------------------------------------- combined head weight prep
// grid = 33 blocks x 256 threads.
__global__ __launch_bounds__(256) void wprep2_k(const float* __restrict__ stats2,
                                                const float* __restrict__ gamma,
                                                const float* __restrict__ beta,
                                                const float* __restrict__ pW,
                                                const float* __restrict__ pb,
                                                unsigned short* __restrict__ pWt,
                                                float* __restrict__ dfin, float invN) {
    __shared__ float sA[HD], sC[HD];
    int f = threadIdx.x;
    if (f < HD) {
        float mean = stats2[f] * invN;
        float var  = stats2[HD + f] * invN - mean * mean;
        float a    = gamma[f] * rsqrtf(var + EPSV);
        sA[f] = a;
        sC[f] = beta[f] - mean * a;
    }
    __syncthreads();
    int b = blockIdx.x, tid = threadIdx.x;
    if (b < 32) {                  // pW: 128x64, scale row k by sA[k]
        int i = b * 256 + tid, k = i >> 6, j = i & 63;
        pWt[(size_t)j * HD + k] = f2bf(pW[i] * sA[k]);
    } else {                       // dfin[j] = pb[j] + sum_f sC[f]*pW[f,j]
        if (tid < OUTD) {
            float s = pb[tid];
            for (int ff = 0; ff < HD; ff++) s += sC[ff] * pW[ff * OUTD + tid];
            dfin[tid] = s;
        }
    }
}

// ------------------------------------------------------------ MFMA bf16 GEMM
// C[n,M] = A[n,K] @ Bt^T (+outBias) (relu?); A bf16, Bt is [M][K] bf16.
// Block: 256 thr (4 waves), tile 128 x M.
template <int K, int M, bool RELU_OUT, bool OUT_BF16>
__global__ __launch_bounds__(256) void mgemm_k(const unsigned short* __restrict__ A,
                                               const unsigned short* __restrict__ Bt,
                                               const float* __restrict__ outBias,
                                               void* __restrict__ Craw, int n) {
    constexpr int BK  = 64;
    constexpr int LDA = BK + 8;                 // 72 ushorts = 144 B row stride
    __shared__ unsigned short As[128 * LDA];
    __shared__ unsigned short Bs[M * LDA];

    const int tid  = threadIdx.x;
    const int wave = tid >> 6, lane = tid & 63;
    const int quad = lane >> 4, mrow = lane & 15;
    const int row0 = blockIdx.x * 128;

    constexpr int RT = (M == 128) ? 4 : 2;
    constexpr int CT = 4;
    const int rowbase = (M == 128) ? ((wave >> 1) * 64) : (wave * 32);
    const int colbase = (M == 128) ? ((wave & 1) * 64) : 0;

    f32x4 acc[RT][CT];
#pragma unroll
    for (int i = 0; i < RT; i++)
#pragma unroll
        for (int j = 0; j < CT; j++) acc[i][j] = (f32x4){0.f, 0.f, 0.f, 0.f};

    for (int k0 = 0; k0 < K; k0 += BK) {
        // ---- stage A tile: 128 rows x 64 cols bf16, pure uint4 copy
#pragma unroll
        for (int p = 0; p < 4; p++) {
            int c   = p * 256 + tid;
            int r   = c >> 3;
            int c8  = (c & 7) * 8;
            int grow = row0 + r;
            uint4 u = make_uint4(0, 0, 0, 0);
            if (grow < n) u = *(const uint4*)&A[(size_t)grow * K + k0 + c8];
            *(uint4*)&As[r * LDA + c8] = u;
        }
        // ---- stage B tile: M rows x 64 cols
#pragma unroll
        for (int p = 0; p < M / 32; p++) {
            int c  = p * 256 + tid;
            int r  = c >> 3;
            int c8 = (c & 7) * 8;
            *(uint4*)&Bs[r * LDA + c8] = *(const uint4*)&Bt[(size_t)r * K + k0 + c8];
        }
        __syncthreads();

#pragma unroll
        for (int ks = 0; ks < BK; ks += 32) {
            bf16x8 af[RT], bfr[CT];
#pragma unroll
            for (int i = 0; i < RT; i++)
                af[i] = *(const bf16x8*)&As[(rowbase + i * 16 + mrow) * LDA + ks + quad * 8];
#pragma unroll
            for (int j = 0; j < CT; j++)
                bfr[j] = *(const bf16x8*)&Bs[(colbase + j * 16 + mrow) * LDA + ks + quad * 8];
#pragma unroll
            for (int i = 0; i < RT; i++)
#pragma unroll
                for (int j = 0; j < CT; j++)
                    acc[i][j] = __builtin_amdgcn_mfma_f32_16x16x32_bf16(
                        af[i], bfr[j], acc[i][j], 0, 0, 0);
        }
        __syncthreads();
    }

    // ---- epilogue: D[row=quad*4+r][col=lane&15] per 16x16 tile
#pragma unroll
    for (int i = 0; i < RT; i++) {
#pragma unroll
        for (int r = 0; r < 4; r++) {
            int row = row0 + rowbase + i * 16 + quad * 4 + r;
            if (row < n) {
#pragma unroll
                for (int j = 0; j < CT; j++) {
                    int col = colbase + j * 16 + mrow;
                    float v = acc[i][j][r];
                    if (outBias) v += outBias[col];
                    if (RELU_OUT) v = fmaxf(v, 0.f);
                    if (OUT_BF16)
                        ((unsigned short*)Craw)[(size_t)row * M + col] = f2bf(v);
                    else
                        ((float*)Craw)[(size_t)row * M + col] = v;
                }
            }
        }
    }
}

// -------------------------------------------------- CSR gather aggregation
// one wave per dst node; bf16 gather, fp32 accumulate, epilogue relu(v+bias)
// written once as bf16. Predicated 4-wide batches keep 4 loads in flight
// through the tail (avg degree = 6).
__global__ __launch_bounds__(256) void agg_csr16_k(const unsigned short* __restrict__ t,
                                                   const int* __restrict__ rowptr,
                                                   const int* __restrict__ esrc,
                                                   const float* __restrict__ enrm,
                                                   const float* __restrict__ bias,
                                                   unsigned short* __restrict__ agg,
                                                   int n) {
    int wid  = (blockIdx.x * blockDim.x + threadIdx.x) >> 6;
    int lane = threadIdx.x & 63;
    if (wid >= n) return;
    int beg = rowptr[wid], end = rowptr[wid + 1];
    float ax[4] = {0.f, 0.f, 0.f, 0.f}, ay[4] = {0.f, 0.f, 0.f, 0.f};
    const unsigned short* tl = t + lane * 2;
    for (int i = beg; i < end; i += 4) {
        int   sdx[4]; float w[4];
#pragma unroll
        for (int k = 0; k < 4; k++) {
            int idx = i + k;
            bool ok = idx < end;
            sdx[k] = esrc[ok ? idx : beg];
            w[k]   = ok ? enrm[idx] : 0.f;
        }
#pragma unroll
        for (int k = 0; k < 4; k++) {
            unsigned int v = *(const unsigned int*)&tl[(size_t)sdx[k] * HD];
            ax[k] += w[k] * bf2f((unsigned short)(v & 0xffff));
            ay[k] += w[k] * bf2f((unsigned short)(v >> 16));
        }
    }
    float rx = (ax[0] + ax[1]) + (ax[2] + ax[3]) + bias[lane * 2];
    float ry = (ay[0] + ay[1]) + (ay[2] + ay[3]) + bias[lane * 2 + 1];
    rx = fmaxf(rx, 0.f);
    ry = fmaxf(ry, 0.f);
    unsigned int o = (unsigned int)f2bf(rx) | ((unsigned int)f2bf(ry) << 16);
    *(unsigned int*)&agg[(size_t)wid * HD + lane * 2] = o;
}

// ============================================================== host driver
extern "C" void kernel_launch(void* const* d_in, const int* in_sizes, int n_in,
                              void* d_out, int out_size, void* d_ws, size_t ws_size,
                              hipStream_t stream) {
    const float* x        = (const float*)d_in[0];
    const int*   ei       = (const int*)d_in[1];   // [2, E] int32
    const float* ew       = (const float*)d_in[2];
    const float* bn_gamma = (const float*)d_in[3];
    const float* bn_beta  = (const float*)d_in[4];
    const float* W0       = (const float*)d_in[5];
    const float* b0       = (const float*)d_in[6];
    const float* W1       = (const float*)d_in[7];
    const float* b1       = (const float*)d_in[8];
    const float* W2       = (const float*)d_in[9];
    const float* b2       = (const float*)d_in[10];
    const float* pgamma   = (const float*)d_in[11];
    const float* pbeta    = (const float*)d_in[12];
    const float* pW       = (const float*)d_in[13];
    const float* pb       = (const float*)d_in[14];
    float* out = (float*)d_out;

    const int* srcp = ei;
    const int* dstp = ei + NEDGE;

    char*  base = (char*)d_ws;
    size_t off  = 0;
    auto carve = [&](size_t bytes) -> void* {
        void* p = (void*)(base + off);
        off = (off + bytes + 255) & ~(size_t)255;
        return p;
    };
    // deg+cnt adjacent (one memset); stats+stats2 adjacent (one memset)
    float*          deg    = (float*)carve(NN * 4);
    int*            cnt    = (int*)carve(NN * 4);
    float*          stats  = (float*)carve(2 * INDIM * 4);
    float*          stats2 = (float*)carve(2 * HD * 4);
    int*            rowptr = (int*)carve((NN + 1) * 4);
    int*            cursor = (int*)carve(NN * 4);
    int*            bsum   = (int*)carve(512 * 4);
    int*            esrc   = (int*)carve(NEDGE * 4);
    float*          enrm   = (float*)carve(NEDGE * 4);
    float*          d0     = (float*)carve(HD * 4);
    float*          dfin   = (float*)carve(OUTD * 4);
    unsigned short* W0t    = (unsigned short*)carve((size_t)INDIM * HD * 2);
    unsigned short* W1t    = (unsigned short*)carve((size_t)HD * HD * 2);
    unsigned short* W2t    = (unsigned short*)carve((size_t)HD * HD * 2);
    unsigned short* pWt    = (unsigned short*)carve((size_t)HD * OUTD * 2);
    unsigned short* xb     = (unsigned short*)carve((size_t)NN * INDIM * 2);
    unsigned short* tbuf   = (unsigned short*)carve((size_t)NN * HD * 2);
    unsigned short* aggb   = (unsigned short*)carve((size_t)NN * HD * 2);
    (void)ws_size;

    const int eBlocks  = (NEDGE + 255) / 256;
    const int nBlocks  = (NN + 255) / 256;        // 391 <= 512
    const int gemmGrid = (NN + 127) / 128;        // 782
    const int aggGrid  = (NN * 64 + 255) / 256;   // one wave per node

    // ---- zero deg+cnt (adjacent) and stats+stats2 (adjacent)
    hipMemsetAsync(deg, 0, (size_t)((char*)cnt - (char*)deg) + NN * 4, stream);
    hipMemsetAsync(stats, 0, (size_t)((char*)stats2 - (char*)stats) + 2 * HD * 4, stream);

    // ---- degree+hist, CSR build, scatter w/ inline norm
    deghist_k<<<eBlocks, 256, 0, stream>>>(dstp, ew, deg, cnt, NEDGE);
    scan1_k<<<nBlocks, 256, 0, stream>>>(cnt, rowptr, bsum, NN);
    scan2_k<<<1, 512, 0, stream>>>(bsum, nBlocks);
    scan3_k<<<nBlocks, 256, 0, stream>>>(rowptr, bsum, cursor, NN);
    scatter_k<<<eBlocks, 256, 0, stream>>>(srcp, dstp, ew, deg, cursor, esrc, enrm, NEDGE);

    // ---- BN(x) stats (+ bf16 copy of x); combined weight prep
    bn_stats_x_k<<<1024, 256, 0, stream>>>(x, stats, xb, NN);
    wprep1_k<<<257, 256, 0, stream>>>(stats, bn_gamma, bn_beta, W0, W1, W2,
                                      W0t, W1t, W2t, d0, 1.f / NN);

    // ---- layer 0: t = xb @ W0t^T + d0 ; agg -> relu(agg + b0)
    mgemm_k<INDIM, HD, false, true><<<gemmGrid, 256, 0, stream>>>(
        xb, W0t, d0, tbuf, NN);
    agg_csr16_k<<<aggGrid, 256, 0, stream>>>(tbuf, rowptr, esrc, enrm, b0, aggb, NN);

    // ---- layer 1
    mgemm_k<HD, HD, false, true><<<gemmGrid, 256, 0, stream>>>(
        aggb, W1t, nullptr, tbuf, NN);
    agg_csr16_k<<<aggGrid, 256, 0, stream>>>(tbuf, rowptr, esrc, enrm, b1, aggb, NN);

    // ---- layer 2
    mgemm_k<HD, HD, false, true><<<gemmGrid, 256, 0, stream>>>(
        aggb, W2t, nullptr, tbuf, NN);
    agg_csr16_k<<<aggGrid, 256, 0, stream>>>(tbuf, rowptr, esrc, enrm, b2, aggb, NN);

    // ---- head: BN(aggb) -> Linear -> ReLU   (aggb already = relu(agg+b2))
    bn_stats16_k<<<512, 256, 0, stream>>>(aggb, stats2, NN);
    wprep2_k<<<33, 256, 0, stream>>>(stats2, pgamma, pbeta, pW, pb, pWt, dfin,
                                     1.f / NN);
    mgemm_k<HD, OUTD, true, false><<<gemmGrid, 256, 0, stream>>>(
        aggb, pWt, dfin, out, NN);

    (void)n_in; (void)in_sizes; (void)out_size;
}

// Round 6
// 484.218 us; speedup vs baseline: 4.5658x; 1.0933x over previous
//
#include <hip/hip_runtime.h>

// GCN forward: BN(x) -> [GCNConv+ReLU] x3 -> BN -> Linear+ReLU
// N=100000 nodes, E=600000 edges, dims 256->128->128->128->64, fp32 in/out.
//
// R6: aggregation restructured to 16-lane groups (4 nodes/wave, uint4 row
// gathers = 4x fewer VMEM issues, 4-deep edge batching = up to 16 gathers in
// flight/wave); edge (src,norm) packed into one uint2 array.

constexpr int NN     = 100000;
constexpr int NEDGE  = 600000;
constexpr int INDIM  = 256;
constexpr int HD     = 128;
constexpr int OUTD   = 64;
#define EPSV 1e-5f

typedef __bf16 bf16x8 __attribute__((ext_vector_type(8)));
typedef float  f32x4  __attribute__((ext_vector_type(4)));

__device__ __forceinline__ float bf2f(unsigned short u) {
    unsigned int v = ((unsigned int)u) << 16;
    return __builtin_bit_cast(float, v);
}
__device__ __forceinline__ unsigned short f2bf(float f) {
    __bf16 h = (__bf16)f;                       // RNE convert
    return __builtin_bit_cast(unsigned short, h);
}
__device__ __forceinline__ void atomAdd(float* p, float v) {
    unsafeAtomicAdd(p, v);
}

// --------------------------------------------- degree + edge-count (fused)
__global__ __launch_bounds__(256) void deghist_k(const int* __restrict__ dst,
                                                 const float* __restrict__ ew,
                                                 float* __restrict__ deg,
                                                 int* __restrict__ cnt, int e) {
    int i = blockIdx.x * blockDim.x + threadIdx.x;
    if (i < e) {
        int d = dst[i];
        atomAdd(&deg[d], ew[i]);
        atomicAdd(&cnt[d], 1);
    }
}

// ------------------------------------------------------------- CSR scans
__global__ __launch_bounds__(256) void scan1_k(const int* __restrict__ cnt,
                                               int* __restrict__ rowptr,
                                               int* __restrict__ bsum, int n) {
    __shared__ int s[256];
    int i = blockIdx.x * 256 + threadIdx.x;
    s[threadIdx.x] = (i < n) ? cnt[i] : 0;
    __syncthreads();
    for (int d = 1; d < 256; d <<= 1) {
        int t = (threadIdx.x >= d) ? s[threadIdx.x - d] : 0;
        __syncthreads();
        s[threadIdx.x] += t;
        __syncthreads();
    }
    if (i < n) rowptr[i + 1] = s[threadIdx.x];
    if (threadIdx.x == 255) bsum[blockIdx.x] = s[255];
}

__global__ __launch_bounds__(512) void scan2_k(int* __restrict__ bsum, int nb) {
    __shared__ int s[512];
    s[threadIdx.x] = (threadIdx.x < (unsigned)nb) ? bsum[threadIdx.x] : 0;
    __syncthreads();
    for (int d = 1; d < 512; d <<= 1) {
        int t = (threadIdx.x >= d) ? s[threadIdx.x - d] : 0;
        __syncthreads();
        s[threadIdx.x] += t;
        __syncthreads();
    }
    if (threadIdx.x < (unsigned)nb) bsum[threadIdx.x] = s[threadIdx.x];
}

__global__ __launch_bounds__(256) void scan3_k(int* __restrict__ rowptr,
                                               const int* __restrict__ bsum,
                                               int* __restrict__ cursor, int n) {
    int i = blockIdx.x * 256 + threadIdx.x;
    if (i == 0) { rowptr[0] = 0; cursor[0] = 0; }
    if (i < n) {
        int v = rowptr[i + 1];
        if (blockIdx.x > 0) v += bsum[blockIdx.x - 1];
        rowptr[i + 1] = v;
        if (i + 1 < n) cursor[i + 1] = v;
    }
}

// ------------- scatter into CSR order; (src, norm) packed into one uint2
__global__ __launch_bounds__(256) void scatter_k(const int* __restrict__ src,
                                                 const int* __restrict__ dst,
                                                 const float* __restrict__ ew,
                                                 const float* __restrict__ deg,
                                                 int* __restrict__ cursor,
                                                 uint2* __restrict__ edata, int e) {
    int i = blockIdx.x * blockDim.x + threadIdx.x;
    if (i < e) {
        int s = src[i], d = dst[i];
        float ds = deg[s], dd = deg[d];
        float is = ds > 0.f ? rsqrtf(fmaxf(ds, EPSV)) : 0.f;
        float id = dd > 0.f ? rsqrtf(fmaxf(dd, EPSV)) : 0.f;
        float nm = is * ew[i] * id;
        int p = atomicAdd(&cursor[d], 1);
        edata[p] = make_uint2((unsigned)s, __builtin_bit_cast(unsigned, nm));
    }
}

// ------------------------------------------- BN stats over x (fp32, DIM=256)
// 4x row-unrolled; also emits bf16 copy of x.
__global__ __launch_bounds__(256) void bn_stats_x_k(const float* __restrict__ in,
                                                    float* __restrict__ sums,
                                                    unsigned short* __restrict__ xb,
                                                    int n) {
    const int tid = threadIdx.x;
    const int cg  = tid & 63;       // float4 chunk within row (256 = 64*4)
    const int rs  = tid >> 6;       // 0..3
    float s0 = 0.f, s1 = 0.f, s2 = 0.f, s3 = 0.f;
    float q0 = 0.f, q1 = 0.f, q2 = 0.f, q3 = 0.f;
    for (int r0 = blockIdx.x * 16; r0 < n; r0 += gridDim.x * 16) {
        float4 v[4];
#pragma unroll
        for (int j = 0; j < 4; j++)
            v[j] = *(const float4*)&in[(size_t)(r0 + rs + j * 4) * INDIM + cg * 4];
#pragma unroll
        for (int j = 0; j < 4; j++) {
            s0 += v[j].x; s1 += v[j].y; s2 += v[j].z; s3 += v[j].w;
            q0 += v[j].x * v[j].x; q1 += v[j].y * v[j].y;
            q2 += v[j].z * v[j].z; q3 += v[j].w * v[j].w;
            unsigned int w0 = (unsigned int)f2bf(v[j].x) | ((unsigned int)f2bf(v[j].y) << 16);
            unsigned int w1 = (unsigned int)f2bf(v[j].z) | ((unsigned int)f2bf(v[j].w) << 16);
            *(uint2*)&xb[(size_t)(r0 + rs + j * 4) * INDIM + cg * 4] = make_uint2(w0, w1);
        }
    }
    __shared__ float red[256 * 8];
    red[tid * 8 + 0] = s0; red[tid * 8 + 1] = s1;
    red[tid * 8 + 2] = s2; red[tid * 8 + 3] = s3;
    red[tid * 8 + 4] = q0; red[tid * 8 + 5] = q1;
    red[tid * 8 + 6] = q2; red[tid * 8 + 7] = q3;
    __syncthreads();
    int cgr = tid >> 2, j = tid & 3;
    float a = 0.f, b = 0.f;
#pragma unroll
    for (int r2 = 0; r2 < 4; r2++) {
        a += red[(r2 * 64 + cgr) * 8 + j];
        b += red[(r2 * 64 + cgr) * 8 + 4 + j];
    }
    atomAdd(&sums[tid], a);
    atomAdd(&sums[INDIM + tid], b);
}

// --------------------------------- BN stats over bf16 activations (DIM=128)
__global__ __launch_bounds__(256) void bn_stats16_k(const unsigned short* __restrict__ in,
                                                    float* __restrict__ sums, int n) {
    const int tid = threadIdx.x;
    const int cg  = tid & 15;       // 8-elem chunk within row (128 = 16*8)
    const int rs  = tid >> 4;       // 0..15
    float s[8], q[8];
#pragma unroll
    for (int j = 0; j < 8; j++) { s[j] = 0.f; q[j] = 0.f; }
    for (int r = blockIdx.x * 16 + rs; r < n; r += gridDim.x * 16) {
        uint4 u = *(const uint4*)&in[(size_t)r * HD + cg * 8];
        float v[8];
        v[0] = bf2f((unsigned short)(u.x & 0xffff)); v[1] = bf2f((unsigned short)(u.x >> 16));
        v[2] = bf2f((unsigned short)(u.y & 0xffff)); v[3] = bf2f((unsigned short)(u.y >> 16));
        v[4] = bf2f((unsigned short)(u.z & 0xffff)); v[5] = bf2f((unsigned short)(u.z >> 16));
        v[6] = bf2f((unsigned short)(u.w & 0xffff)); v[7] = bf2f((unsigned short)(u.w >> 16));
#pragma unroll
        for (int j = 0; j < 8; j++) { s[j] += v[j]; q[j] += v[j] * v[j]; }
    }
    __shared__ float red[256 * 16];
#pragma unroll
    for (int j = 0; j < 8; j++) {
        red[tid * 16 + j]     = s[j];
        red[tid * 16 + 8 + j] = q[j];
    }
    __syncthreads();
    if (tid < HD) {
        int cgr = tid >> 3, j = tid & 7;
        float a = 0.f, b = 0.f;
#pragma unroll
        for (int r2 = 0; r2 < 16; r2++) {
            a += red[(r2 * 16 + cgr) * 16 + j];
            b += red[(r2 * 16 + cgr) * 16 + 8 + j];
        }
        atomAdd(&sums[tid], a);
        atomAdd(&sums[HD + tid], b);
    }
}

// ------------------------------------------ combined weight prep, layer 0-2
__global__ __launch_bounds__(256) void wprep1_k(const float* __restrict__ stats,
                                                const float* __restrict__ gamma,
                                                const float* __restrict__ beta,
                                                const float* __restrict__ W0,
                                                const float* __restrict__ W1,
                                                const float* __restrict__ W2,
                                                unsigned short* __restrict__ W0t,
                                                unsigned short* __restrict__ W1t,
                                                unsigned short* __restrict__ W2t,
                                                float* __restrict__ d0, float invN) {
    __shared__ float sA[INDIM], sC[INDIM];
    int f = threadIdx.x;
    {
        float mean = stats[f] * invN;
        float var  = stats[INDIM + f] * invN - mean * mean;
        float a    = gamma[f] * rsqrtf(var + EPSV);
        sA[f] = a;
        sC[f] = beta[f] - mean * a;
    }
    __syncthreads();
    int b = blockIdx.x, tid = threadIdx.x;
    if (b < 128) {                 // W0: 256x128, scale row k by sA[k]
        int i = b * 256 + tid, k = i >> 7, j = i & 127;
        W0t[(size_t)j * INDIM + k] = f2bf(W0[i] * sA[k]);
    } else if (b < 192) {          // W1: 128x128
        int i = (b - 128) * 256 + tid, k = i >> 7, j = i & 127;
        W1t[(size_t)j * HD + k] = f2bf(W1[i]);
    } else if (b < 256) {          // W2: 128x128
        int i = (b - 192) * 256 + tid, k = i >> 7, j = i & 127;
        W2t[(size_t)j * HD + k] = f2bf(W2[i]);
    } else {                       // d0[j] = sum_f sC[f]*W0[f,j]
        if (tid < HD) {
            float s = 0.f;
            for (int ff = 0; ff < INDIM; ff++) s += sC[ff] * W0[ff * HD + tid];
            d0[tid] = s;
        }
    }
}

// ------------------------------------------------- combined head weight prep
__global__ __launch_bounds__(256) void wprep2_k(const float* __restrict__ stats2,
                                                const float* __restrict__ gamma,
                                                const float* __restrict__ beta,
                                                const float* __restrict__ pW,
                                                const float* __restrict__ pb,
                                                unsigned short* __restrict__ pWt,
                                                float* __restrict__ dfin, float invN) {
    __shared__ float sA[HD], sC[HD];
    int f = threadIdx.x;
    if (f < HD) {
        float mean = stats2[f] * invN;
        float var  = stats2[HD + f] * invN - mean * mean;
        float a    = gamma[f] * rsqrtf(var + EPSV);
        sA[f] = a;
        sC[f] = beta[f] - mean * a;
    }
    __syncthreads();
    int b = blockIdx.x, tid = threadIdx.x;
    if (b < 32) {                  // pW: 128x64, scale row k by sA[k]
        int i = b * 256 + tid, k = i >> 6, j = i & 63;
        pWt[(size_t)j * HD + k] = f2bf(pW[i] * sA[k]);
    } else {                       // dfin[j] = pb[j] + sum_f sC[f]*pW[f,j]
        if (tid < OUTD) {
            float s = pb[tid];
            for (int ff = 0; ff < HD; ff++) s += sC[ff] * pW[ff * OUTD + tid];
            dfin[tid] = s;
        }
    }
}

// ------------------------------------------------------------ MFMA bf16 GEMM
// C[n,M] = A[n,K] @ Bt^T (+outBias) (relu?); A bf16, Bt is [M][K] bf16.
template <int K, int M, bool RELU_OUT, bool OUT_BF16>
__global__ __launch_bounds__(256) void mgemm_k(const unsigned short* __restrict__ A,
                                               const unsigned short* __restrict__ Bt,
                                               const float* __restrict__ outBias,
                                               void* __restrict__ Craw, int n) {
    constexpr int BK  = 64;
    constexpr int LDA = BK + 8;                 // 72 ushorts = 144 B row stride
    __shared__ unsigned short As[128 * LDA];
    __shared__ unsigned short Bs[M * LDA];

    const int tid  = threadIdx.x;
    const int wave = tid >> 6, lane = tid & 63;
    const int quad = lane >> 4, mrow = lane & 15;
    const int row0 = blockIdx.x * 128;

    constexpr int RT = (M == 128) ? 4 : 2;
    constexpr int CT = 4;
    const int rowbase = (M == 128) ? ((wave >> 1) * 64) : (wave * 32);
    const int colbase = (M == 128) ? ((wave & 1) * 64) : 0;

    f32x4 acc[RT][CT];
#pragma unroll
    for (int i = 0; i < RT; i++)
#pragma unroll
        for (int j = 0; j < CT; j++) acc[i][j] = (f32x4){0.f, 0.f, 0.f, 0.f};

    for (int k0 = 0; k0 < K; k0 += BK) {
#pragma unroll
        for (int p = 0; p < 4; p++) {
            int c   = p * 256 + tid;
            int r   = c >> 3;
            int c8  = (c & 7) * 8;
            int grow = row0 + r;
            uint4 u = make_uint4(0, 0, 0, 0);
            if (grow < n) u = *(const uint4*)&A[(size_t)grow * K + k0 + c8];
            *(uint4*)&As[r * LDA + c8] = u;
        }
#pragma unroll
        for (int p = 0; p < M / 32; p++) {
            int c  = p * 256 + tid;
            int r  = c >> 3;
            int c8 = (c & 7) * 8;
            *(uint4*)&Bs[r * LDA + c8] = *(const uint4*)&Bt[(size_t)r * K + k0 + c8];
        }
        __syncthreads();

#pragma unroll
        for (int ks = 0; ks < BK; ks += 32) {
            bf16x8 af[RT], bfr[CT];
#pragma unroll
            for (int i = 0; i < RT; i++)
                af[i] = *(const bf16x8*)&As[(rowbase + i * 16 + mrow) * LDA + ks + quad * 8];
#pragma unroll
            for (int j = 0; j < CT; j++)
                bfr[j] = *(const bf16x8*)&Bs[(colbase + j * 16 + mrow) * LDA + ks + quad * 8];
#pragma unroll
            for (int i = 0; i < RT; i++)
#pragma unroll
                for (int j = 0; j < CT; j++)
                    acc[i][j] = __builtin_amdgcn_mfma_f32_16x16x32_bf16(
                        af[i], bfr[j], acc[i][j], 0, 0, 0);
        }
        __syncthreads();
    }

#pragma unroll
    for (int i = 0; i < RT; i++) {
#pragma unroll
        for (int r = 0; r < 4; r++) {
            int row = row0 + rowbase + i * 16 + quad * 4 + r;
            if (row < n) {
#pragma unroll
                for (int j = 0; j < CT; j++) {
                    int col = colbase + j * 16 + mrow;
                    float v = acc[i][j][r];
                    if (outBias) v += outBias[col];
                    if (RELU_OUT) v = fmaxf(v, 0.f);
                    if (OUT_BF16)
                        ((unsigned short*)Craw)[(size_t)row * M + col] = f2bf(v);
                    else
                        ((float*)Craw)[(size_t)row * M + col] = v;
                }
            }
        }
    }
}

// -------------------------------------------------- CSR gather aggregation
// 16-lane groups: each group owns one node, lane covers 8 cols (uint4 = 16B).
// 4 nodes/wave, 16 nodes/block. 4-deep predicated edge batches -> up to 16
// row-gathers in flight per wave. Epilogue: relu(acc + bias) once, bf16.
__global__ __launch_bounds__(256) void agg_csr16_k(const unsigned short* __restrict__ t,
                                                   const int* __restrict__ rowptr,
                                                   const uint2* __restrict__ edata,
                                                   const float* __restrict__ bias,
                                                   unsigned short* __restrict__ agg,
                                                   int n) {
    const int tid  = threadIdx.x;
    const int g    = tid >> 4;          // node-group within block: 0..15
    const int gl   = tid & 15;          // lane within group: 8 cols each
    const int node = blockIdx.x * 16 + g;
    if (node >= n) return;
    const int beg = rowptr[node], end = rowptr[node + 1];
    float acc[8];
#pragma unroll
    for (int j = 0; j < 8; j++) acc[j] = 0.f;
    const unsigned short* tg = t + gl * 8;
    for (int i = beg; i < end; i += 4) {
        uint4 v[4]; float w[4];
#pragma unroll
        for (int k = 0; k < 4; k++) {
            int  idx = i + k;
            bool ok  = idx < end;
            uint2 ed = edata[ok ? idx : beg];
            w[k] = ok ? __builtin_bit_cast(float, ed.y) : 0.f;
            v[k] = *(const uint4*)&tg[(size_t)ed.x * HD];
        }
#pragma unroll
        for (int k = 0; k < 4; k++) {
            acc[0] += w[k] * bf2f((unsigned short)(v[k].x & 0xffff));
            acc[1] += w[k] * bf2f((unsigned short)(v[k].x >> 16));
            acc[2] += w[k] * bf2f((unsigned short)(v[k].y & 0xffff));
            acc[3] += w[k] * bf2f((unsigned short)(v[k].y >> 16));
            acc[4] += w[k] * bf2f((unsigned short)(v[k].z & 0xffff));
            acc[5] += w[k] * bf2f((unsigned short)(v[k].z >> 16));
            acc[6] += w[k] * bf2f((unsigned short)(v[k].w & 0xffff));
            acc[7] += w[k] * bf2f((unsigned short)(v[k].w >> 16));
        }
    }
    float4 b0 = *(const float4*)&bias[gl * 8];
    float4 b1 = *(const float4*)&bias[gl * 8 + 4];
    float r0 = fmaxf(acc[0] + b0.x, 0.f), r1 = fmaxf(acc[1] + b0.y, 0.f);
    float r2 = fmaxf(acc[2] + b0.z, 0.f), r3 = fmaxf(acc[3] + b0.w, 0.f);
    float r4 = fmaxf(acc[4] + b1.x, 0.f), r5 = fmaxf(acc[5] + b1.y, 0.f);
    float r6 = fmaxf(acc[6] + b1.z, 0.f), r7 = fmaxf(acc[7] + b1.w, 0.f);
    uint4 o;
    o.x = (unsigned int)f2bf(r0) | ((unsigned int)f2bf(r1) << 16);
    o.y = (unsigned int)f2bf(r2) | ((unsigned int)f2bf(r3) << 16);
    o.z = (unsigned int)f2bf(r4) | ((unsigned int)f2bf(r5) << 16);
    o.w = (unsigned int)f2bf(r6) | ((unsigned int)f2bf(r7) << 16);
    *(uint4*)&agg[(size_t)node * HD + gl * 8] = o;
}

// ============================================================== host driver
extern "C" void kernel_launch(void* const* d_in, const int* in_sizes, int n_in,
                              void* d_out, int out_size, void* d_ws, size_t ws_size,
                              hipStream_t stream) {
    const float* x        = (const float*)d_in[0];
    const int*   ei       = (const int*)d_in[1];   // [2, E] int32
    const float* ew       = (const float*)d_in[2];
    const float* bn_gamma = (const float*)d_in[3];
    const float* bn_beta  = (const float*)d_in[4];
    const float* W0       = (const float*)d_in[5];
    const float* b0       = (const float*)d_in[6];
    const float* W1       = (const float*)d_in[7];
    const float* b1       = (const float*)d_in[8];
    const float* W2       = (const float*)d_in[9];
    const float* b2       = (const float*)d_in[10];
    const float* pgamma   = (const float*)d_in[11];
    const float* pbeta    = (const float*)d_in[12];
    const float* pW       = (const float*)d_in[13];
    const float* pb       = (const float*)d_in[14];
    float* out = (float*)d_out;

    const int* srcp = ei;
    const int* dstp = ei + NEDGE;

    char*  base = (char*)d_ws;
    size_t off  = 0;
    auto carve = [&](size_t bytes) -> void* {
        void* p = (void*)(base + off);
        off = (off + bytes + 255) & ~(size_t)255;
        return p;
    };
    float*          deg    = (float*)carve(NN * 4);
    int*            cnt    = (int*)carve(NN * 4);
    float*          stats  = (float*)carve(2 * INDIM * 4);
    float*          stats2 = (float*)carve(2 * HD * 4);
    int*            rowptr = (int*)carve((NN + 1) * 4);
    int*            cursor = (int*)carve(NN * 4);
    int*            bsum   = (int*)carve(512 * 4);
    uint2*          edata  = (uint2*)carve((size_t)NEDGE * 8);
    float*          d0     = (float*)carve(HD * 4);
    float*          dfin   = (float*)carve(OUTD * 4);
    unsigned short* W0t    = (unsigned short*)carve((size_t)INDIM * HD * 2);
    unsigned short* W1t    = (unsigned short*)carve((size_t)HD * HD * 2);
    unsigned short* W2t    = (unsigned short*)carve((size_t)HD * HD * 2);
    unsigned short* pWt    = (unsigned short*)carve((size_t)HD * OUTD * 2);
    unsigned short* xb     = (unsigned short*)carve((size_t)NN * INDIM * 2);
    unsigned short* tbuf   = (unsigned short*)carve((size_t)NN * HD * 2);
    unsigned short* aggb   = (unsigned short*)carve((size_t)NN * HD * 2);
    (void)ws_size;

    const int eBlocks  = (NEDGE + 255) / 256;
    const int nBlocks  = (NN + 255) / 256;        // 391 <= 512
    const int gemmGrid = (NN + 127) / 128;        // 782
    const int aggGrid  = (NN + 15) / 16;          // 16 nodes per block

    // ---- zero deg+cnt (adjacent) and stats+stats2 (adjacent)
    hipMemsetAsync(deg, 0, (size_t)((char*)cnt - (char*)deg) + NN * 4, stream);
    hipMemsetAsync(stats, 0, (size_t)((char*)stats2 - (char*)stats) + 2 * HD * 4, stream);

    // ---- degree+hist, CSR build, scatter w/ inline norm
    deghist_k<<<eBlocks, 256, 0, stream>>>(dstp, ew, deg, cnt, NEDGE);
    scan1_k<<<nBlocks, 256, 0, stream>>>(cnt, rowptr, bsum, NN);
    scan2_k<<<1, 512, 0, stream>>>(bsum, nBlocks);
    scan3_k<<<nBlocks, 256, 0, stream>>>(rowptr, bsum, cursor, NN);
    scatter_k<<<eBlocks, 256, 0, stream>>>(srcp, dstp, ew, deg, cursor, edata, NEDGE);

    // ---- BN(x) stats (+ bf16 copy of x); combined weight prep
    bn_stats_x_k<<<1024, 256, 0, stream>>>(x, stats, xb, NN);
    wprep1_k<<<257, 256, 0, stream>>>(stats, bn_gamma, bn_beta, W0, W1, W2,
                                      W0t, W1t, W2t, d0, 1.f / NN);

    // ---- layer 0: t = xb @ W0t^T + d0 ; agg -> relu(agg + b0)
    mgemm_k<INDIM, HD, false, true><<<gemmGrid, 256, 0, stream>>>(
        xb, W0t, d0, tbuf, NN);
    agg_csr16_k<<<aggGrid, 256, 0, stream>>>(tbuf, rowptr, edata, b0, aggb, NN);

    // ---- layer 1
    mgemm_k<HD, HD, false, true><<<gemmGrid, 256, 0, stream>>>(
        aggb, W1t, nullptr, tbuf, NN);
    agg_csr16_k<<<aggGrid, 256, 0, stream>>>(tbuf, rowptr, edata, b1, aggb, NN);

    // ---- layer 2
    mgemm_k<HD, HD, false, true><<<gemmGrid, 256, 0, stream>>>(
        aggb, W2t, nullptr, tbuf, NN);
    agg_csr16_k<<<aggGrid, 256, 0, stream>>>(tbuf, rowptr, edata, b2, aggb, NN);

    // ---- head: BN(aggb) -> Linear -> ReLU   (aggb already = relu(agg+b2))
    bn_stats16_k<<<512, 256, 0, stream>>>(aggb, stats2, NN);
    wprep2_k<<<33, 256, 0, stream>>>(stats2, pgamma, pbeta, pW, pb, pWt, dfin,
                                     1.f / NN);
    mgemm_k<HD, OUTD, true, false><<<gemmGrid, 256, 0, stream>>>(
        aggb, pWt, dfin, out, NN);

    (void)n_in; (void)in_sizes; (void)out_size;
}

// Round 7
// 474.184 us; speedup vs baseline: 4.6624x; 1.0212x over previous
//
#include <hip/hip_runtime.h>

// GCN forward: BN(x) -> [GCNConv+ReLU] x3 -> BN -> Linear+ReLU
// N=100000 nodes, E=600000 edges, dims 256->128->128->128->64, fp32 in/out.
//
// R7: aggregation fused into GEMM1/GEMM2 A-staging (aggb round-trip gone,
// gather overlaps MFMA); head BN-stats fused into agg2; independent
// front-end kernels merged by block partition (deghist|bn_stats_x,
// scan1|wprep1, scatter|GEMM0); gather batches 8-deep; 11 dispatches.

constexpr int NN    = 100000;
constexpr int NEDGE = 600000;
constexpr int INDIM = 256;
constexpr int HD    = 128;
constexpr int OUTD  = 64;
constexpr int EB    = (NEDGE + 255) / 256;  // 2344 edge blocks
constexpr int SB    = 1024;                 // bn_stats_x blocks
constexpr int NB    = (NN + 255) / 256;     // 391 scan blocks
constexpr int WB    = 257;                  // wprep1 blocks
constexpr int GG    = (NN + 127) / 128;     // 782 gemm blocks
constexpr int A2B   = 1024;                 // agg2 blocks
#define EPSV 1e-5f

typedef __bf16 bf16x8 __attribute__((ext_vector_type(8)));
typedef float  f32x4  __attribute__((ext_vector_type(4)));

__device__ __forceinline__ float bf2f(unsigned short u) {
    unsigned int v = ((unsigned int)u) << 16;
    return __builtin_bit_cast(float, v);
}
__device__ __forceinline__ unsigned short f2bf(float f) {
    __bf16 h = (__bf16)f;                       // RNE convert
    return __builtin_bit_cast(unsigned short, h);
}
__device__ __forceinline__ void atomAdd(float* p, float v) {
    unsafeAtomicAdd(p, v);
}

// ---------------------------------------------------------------- MFMA GEMM
// C[n,M] = A[n,K] @ Bt^T (+outBias) (relu?); A bf16, Bt is [M][K] bf16.
// Device body so it can live inside merged kernels (smem passed in).
template <int K, int M, bool RELU_OUT, bool OUT_BF16>
__device__ __forceinline__ void mgemm_body(int bid, int tid, char* smem,
                                           const unsigned short* __restrict__ A,
                                           const unsigned short* __restrict__ Bt,
                                           const float* __restrict__ outBias,
                                           void* __restrict__ Craw, int n) {
    constexpr int BK  = 64;
    constexpr int LDA = BK + 8;                 // 72 ushorts = 144 B stride
    unsigned short* As = (unsigned short*)smem;         // 128*LDA
    unsigned short* Bs = As + 128 * LDA;                // M*LDA

    const int wave = tid >> 6, lane = tid & 63;
    const int quad = lane >> 4, mrow = lane & 15;
    const int row0 = bid * 128;

    constexpr int RT = (M == 128) ? 4 : 2;
    constexpr int CT = 4;
    const int rowbase = (M == 128) ? ((wave >> 1) * 64) : (wave * 32);
    const int colbase = (M == 128) ? ((wave & 1) * 64) : 0;

    f32x4 acc[RT][CT];
#pragma unroll
    for (int i = 0; i < RT; i++)
#pragma unroll
        for (int j = 0; j < CT; j++) acc[i][j] = (f32x4){0.f, 0.f, 0.f, 0.f};

    for (int k0 = 0; k0 < K; k0 += BK) {
        if (k0) __syncthreads();
#pragma unroll
        for (int p = 0; p < 4; p++) {
            int c   = p * 256 + tid;
            int r   = c >> 3;
            int c8  = (c & 7) * 8;
            int grow = row0 + r;
            uint4 u = make_uint4(0, 0, 0, 0);
            if (grow < n) u = *(const uint4*)&A[(size_t)grow * K + k0 + c8];
            *(uint4*)&As[r * LDA + c8] = u;
        }
#pragma unroll
        for (int p = 0; p < M / 32; p++) {
            int c  = p * 256 + tid;
            int r  = c >> 3;
            int c8 = (c & 7) * 8;
            *(uint4*)&Bs[r * LDA + c8] = *(const uint4*)&Bt[(size_t)r * K + k0 + c8];
        }
        __syncthreads();

#pragma unroll
        for (int ks = 0; ks < BK; ks += 32) {
            bf16x8 af[RT], bfr[CT];
#pragma unroll
            for (int i = 0; i < RT; i++)
                af[i] = *(const bf16x8*)&As[(rowbase + i * 16 + mrow) * LDA + ks + quad * 8];
#pragma unroll
            for (int j = 0; j < CT; j++)
                bfr[j] = *(const bf16x8*)&Bs[(colbase + j * 16 + mrow) * LDA + ks + quad * 8];
#pragma unroll
            for (int i = 0; i < RT; i++)
#pragma unroll
                for (int j = 0; j < CT; j++)
                    acc[i][j] = __builtin_amdgcn_mfma_f32_16x16x32_bf16(
                        af[i], bfr[j], acc[i][j], 0, 0, 0);
        }
    }

#pragma unroll
    for (int i = 0; i < RT; i++) {
#pragma unroll
        for (int r = 0; r < 4; r++) {
            int row = row0 + rowbase + i * 16 + quad * 4 + r;
            if (row < n) {
#pragma unroll
                for (int j = 0; j < CT; j++) {
                    int col = colbase + j * 16 + mrow;
                    float v = acc[i][j][r];
                    if (outBias) v += outBias[col];
                    if (RELU_OUT) v = fmaxf(v, 0.f);
                    if (OUT_BF16)
                        ((unsigned short*)Craw)[(size_t)row * M + col] = f2bf(v);
                    else
                        ((float*)Craw)[(size_t)row * M + col] = v;
                }
            }
        }
    }
}

// ---------------------------------- 8-deep predicated gather-accumulate step
__device__ __forceinline__ void gather8(const unsigned short* __restrict__ tg,
                                        const uint2* __restrict__ edata,
                                        int i, int beg, int end, float* acc) {
    uint4 v[8]; float w[8];
#pragma unroll
    for (int k = 0; k < 8; k++) {
        int  idx = i + k;
        bool ok  = idx < end;
        uint2 ed = edata[ok ? idx : beg];
        w[k] = ok ? __builtin_bit_cast(float, ed.y) : 0.f;
        v[k] = *(const uint4*)&tg[(size_t)ed.x * HD];
    }
#pragma unroll
    for (int k = 0; k < 8; k++) {
        acc[0] += w[k] * bf2f((unsigned short)(v[k].x & 0xffff));
        acc[1] += w[k] * bf2f((unsigned short)(v[k].x >> 16));
        acc[2] += w[k] * bf2f((unsigned short)(v[k].y & 0xffff));
        acc[3] += w[k] * bf2f((unsigned short)(v[k].y >> 16));
        acc[4] += w[k] * bf2f((unsigned short)(v[k].z & 0xffff));
        acc[5] += w[k] * bf2f((unsigned short)(v[k].z >> 16));
        acc[6] += w[k] * bf2f((unsigned short)(v[k].w & 0xffff));
        acc[7] += w[k] * bf2f((unsigned short)(v[k].w >> 16));
    }
}

// ------------------------------------------------ fused agg + GEMM (128x128)
// C = relu(Agg(t) + bias) @ Bt^T.  A-tile produced by CSR gather into LDS.
__global__ __launch_bounds__(256) void fagg_gemm_k(const unsigned short* __restrict__ t,
                                                   const int* __restrict__ rowptr,
                                                   const uint2* __restrict__ edata,
                                                   const float* __restrict__ bias,
                                                   const unsigned short* __restrict__ Bt,
                                                   unsigned short* __restrict__ Cout,
                                                   int n) {
    constexpr int LDAa = HD + 8;                // 136
    constexpr int LDAb = 64 + 8;                // 72
    __shared__ unsigned short As[128 * LDAa];   // 34816 B
    __shared__ unsigned short Bs[HD * LDAb];    // 18432 B

    const int tid  = threadIdx.x;
    const int row0 = blockIdx.x * 128;

    // ---- A staging: 16-lane groups, each group aggregates 8 nodes
    {
        const int g  = tid >> 4;
        const int gl = tid & 15;
        const unsigned short* tg = t + gl * 8;
        float4 bb0 = *(const float4*)&bias[gl * 8];
        float4 bb1 = *(const float4*)&bias[gl * 8 + 4];
        for (int rr = 0; rr < 8; rr++) {
            int node = row0 + g * 8 + rr;
            float acc[8];
#pragma unroll
            for (int j = 0; j < 8; j++) acc[j] = 0.f;
            if (node < n) {
                int beg = rowptr[node], end = rowptr[node + 1];
                for (int i = beg; i < end; i += 8)
                    gather8(tg, edata, i, beg, end, acc);
            }
            float r0 = fmaxf(acc[0] + bb0.x, 0.f), r1 = fmaxf(acc[1] + bb0.y, 0.f);
            float r2 = fmaxf(acc[2] + bb0.z, 0.f), r3 = fmaxf(acc[3] + bb0.w, 0.f);
            float r4 = fmaxf(acc[4] + bb1.x, 0.f), r5 = fmaxf(acc[5] + bb1.y, 0.f);
            float r6 = fmaxf(acc[6] + bb1.z, 0.f), r7 = fmaxf(acc[7] + bb1.w, 0.f);
            uint4 o;
            o.x = (unsigned int)f2bf(r0) | ((unsigned int)f2bf(r1) << 16);
            o.y = (unsigned int)f2bf(r2) | ((unsigned int)f2bf(r3) << 16);
            o.z = (unsigned int)f2bf(r4) | ((unsigned int)f2bf(r5) << 16);
            o.w = (unsigned int)f2bf(r6) | ((unsigned int)f2bf(r7) << 16);
            *(uint4*)&As[(g * 8 + rr) * LDAa + gl * 8] = o;
        }
    }

    // ---- MFMA: B double-staged in two 64-wide K-chunks
    const int wave = tid >> 6, lane = tid & 63;
    const int quad = lane >> 4, mrow = lane & 15;
    const int rowbase = (wave >> 1) * 64;
    const int colbase = (wave & 1) * 64;

    f32x4 acc[4][4];
#pragma unroll
    for (int i = 0; i < 4; i++)
#pragma unroll
        for (int j = 0; j < 4; j++) acc[i][j] = (f32x4){0.f, 0.f, 0.f, 0.f};

    for (int k0 = 0; k0 < HD; k0 += 64) {
        if (k0) __syncthreads();
#pragma unroll
        for (int p = 0; p < 4; p++) {
            int c  = p * 256 + tid;
            int r  = c >> 3;
            int c8 = (c & 7) * 8;
            *(uint4*)&Bs[r * LDAb + c8] = *(const uint4*)&Bt[(size_t)r * HD + k0 + c8];
        }
        __syncthreads();
#pragma unroll
        for (int ks = 0; ks < 64; ks += 32) {
            bf16x8 af[4], bfr[4];
#pragma unroll
            for (int i = 0; i < 4; i++)
                af[i] = *(const bf16x8*)&As[(rowbase + i * 16 + mrow) * LDAa + k0 + ks + quad * 8];
#pragma unroll
            for (int j = 0; j < 4; j++)
                bfr[j] = *(const bf16x8*)&Bs[(colbase + j * 16 + mrow) * LDAb + ks + quad * 8];
#pragma unroll
            for (int i = 0; i < 4; i++)
#pragma unroll
                for (int j = 0; j < 4; j++)
                    acc[i][j] = __builtin_amdgcn_mfma_f32_16x16x32_bf16(
                        af[i], bfr[j], acc[i][j], 0, 0, 0);
        }
    }

#pragma unroll
    for (int i = 0; i < 4; i++) {
#pragma unroll
        for (int r = 0; r < 4; r++) {
            int row = row0 + rowbase + i * 16 + quad * 4 + r;
            if (row < n) {
#pragma unroll
                for (int j = 0; j < 4; j++) {
                    int col = colbase + j * 16 + mrow;
                    Cout[(size_t)row * HD + col] = f2bf(acc[i][j][r]);
                }
            }
        }
    }
}

// ------------------------------- front: deghist (blocks<EB) | bn_stats_x
__global__ __launch_bounds__(256) void front_k(const int* __restrict__ dst,
                                               const float* __restrict__ ew,
                                               float* __restrict__ deg,
                                               int* __restrict__ cnt,
                                               const float* __restrict__ x,
                                               float* __restrict__ sums,
                                               unsigned short* __restrict__ xb) {
    __shared__ float red[256 * 8];
    const int tid = threadIdx.x;
    if (blockIdx.x < EB) {
        int i = blockIdx.x * 256 + tid;
        if (i < NEDGE) {
            int d = dst[i];
            atomAdd(&deg[d], ew[i]);
            atomicAdd(&cnt[d], 1);
        }
        return;
    }
    const int bid = blockIdx.x - EB;            // 0..SB-1
    const int cg  = tid & 63;
    const int rs  = tid >> 6;
    float s0 = 0.f, s1 = 0.f, s2 = 0.f, s3 = 0.f;
    float q0 = 0.f, q1 = 0.f, q2 = 0.f, q3 = 0.f;
    for (int r0 = bid * 16; r0 < NN; r0 += SB * 16) {
        float4 v[4];
#pragma unroll
        for (int j = 0; j < 4; j++)
            v[j] = *(const float4*)&x[(size_t)(r0 + rs + j * 4) * INDIM + cg * 4];
#pragma unroll
        for (int j = 0; j < 4; j++) {
            s0 += v[j].x; s1 += v[j].y; s2 += v[j].z; s3 += v[j].w;
            q0 += v[j].x * v[j].x; q1 += v[j].y * v[j].y;
            q2 += v[j].z * v[j].z; q3 += v[j].w * v[j].w;
            unsigned int w0 = (unsigned int)f2bf(v[j].x) | ((unsigned int)f2bf(v[j].y) << 16);
            unsigned int w1 = (unsigned int)f2bf(v[j].z) | ((unsigned int)f2bf(v[j].w) << 16);
            *(uint2*)&xb[(size_t)(r0 + rs + j * 4) * INDIM + cg * 4] = make_uint2(w0, w1);
        }
    }
    red[tid * 8 + 0] = s0; red[tid * 8 + 1] = s1;
    red[tid * 8 + 2] = s2; red[tid * 8 + 3] = s3;
    red[tid * 8 + 4] = q0; red[tid * 8 + 5] = q1;
    red[tid * 8 + 6] = q2; red[tid * 8 + 7] = q3;
    __syncthreads();
    int cgr = tid >> 2, j = tid & 3;
    float a = 0.f, b = 0.f;
#pragma unroll
    for (int r2 = 0; r2 < 4; r2++) {
        a += red[(r2 * 64 + cgr) * 8 + j];
        b += red[(r2 * 64 + cgr) * 8 + 4 + j];
    }
    atomAdd(&sums[tid], a);
    atomAdd(&sums[INDIM + tid], b);
}

// --------------------------------- mid: scan1 (blocks<NB) | wprep1 (layer W)
__global__ __launch_bounds__(256) void mid_k(const int* __restrict__ cnt,
                                             int* __restrict__ rowptr,
                                             int* __restrict__ bsum,
                                             const float* __restrict__ stats,
                                             const float* __restrict__ gamma,
                                             const float* __restrict__ beta,
                                             const float* __restrict__ W0,
                                             const float* __restrict__ W1,
                                             const float* __restrict__ W2,
                                             unsigned short* __restrict__ W0t,
                                             unsigned short* __restrict__ W1t,
                                             unsigned short* __restrict__ W2t,
                                             float* __restrict__ d0, float invN) {
    __shared__ float sm[512];
    const int tid = threadIdx.x;
    if (blockIdx.x < NB) {
        int* s = (int*)sm;
        int i = blockIdx.x * 256 + tid;
        s[tid] = (i < NN) ? cnt[i] : 0;
        __syncthreads();
        for (int d = 1; d < 256; d <<= 1) {
            int t = (tid >= d) ? s[tid - d] : 0;
            __syncthreads();
            s[tid] += t;
            __syncthreads();
        }
        if (i < NN) rowptr[i + 1] = s[tid];
        if (tid == 255) bsum[blockIdx.x] = s[255];
        return;
    }
    const int b = blockIdx.x - NB;              // 0..WB-1
    float* sA = sm;
    float* sC = sm + 256;
    {
        float mean = stats[tid] * invN;
        float var  = stats[INDIM + tid] * invN - mean * mean;
        float a    = gamma[tid] * rsqrtf(var + EPSV);
        sA[tid] = a;
        sC[tid] = beta[tid] - mean * a;
    }
    __syncthreads();
    if (b < 128) {                 // W0: 256x128, scale row k by sA[k]
        int i = b * 256 + tid, k = i >> 7, j = i & 127;
        W0t[(size_t)j * INDIM + k] = f2bf(W0[i] * sA[k]);
    } else if (b < 192) {          // W1: 128x128
        int i = (b - 128) * 256 + tid, k = i >> 7, j = i & 127;
        W1t[(size_t)j * HD + k] = f2bf(W1[i]);
    } else if (b < 256) {          // W2: 128x128
        int i = (b - 192) * 256 + tid, k = i >> 7, j = i & 127;
        W2t[(size_t)j * HD + k] = f2bf(W2[i]);
    } else {                       // d0[j] = sum_f sC[f]*W0[f,j]
        if (tid < HD) {
            float s = 0.f;
            for (int ff = 0; ff < INDIM; ff++) s += sC[ff] * W0[ff * HD + tid];
            d0[tid] = s;
        }
    }
}

// ------------------------------------------------------------- CSR scans 2,3
__global__ __launch_bounds__(512) void scan2_k(int* __restrict__ bsum, int nb) {
    __shared__ int s[512];
    s[threadIdx.x] = (threadIdx.x < (unsigned)nb) ? bsum[threadIdx.x] : 0;
    __syncthreads();
    for (int d = 1; d < 512; d <<= 1) {
        int t = (threadIdx.x >= d) ? s[threadIdx.x - d] : 0;
        __syncthreads();
        s[threadIdx.x] += t;
        __syncthreads();
    }
    if (threadIdx.x < (unsigned)nb) bsum[threadIdx.x] = s[threadIdx.x];
}

__global__ __launch_bounds__(256) void scan3_k(int* __restrict__ rowptr,
                                               const int* __restrict__ bsum,
                                               int* __restrict__ cursor, int n) {
    int i = blockIdx.x * 256 + threadIdx.x;
    if (i == 0) { rowptr[0] = 0; cursor[0] = 0; }
    if (i < n) {
        int v = rowptr[i + 1];
        if (blockIdx.x > 0) v += bsum[blockIdx.x - 1];
        rowptr[i + 1] = v;
        if (i + 1 < n) cursor[i + 1] = v;
    }
}

// ----------------------------- sg0: scatter (blocks<EB) | GEMM0 (xb @ W0t)
__global__ __launch_bounds__(256) void sg0_k(const int* __restrict__ src,
                                             const int* __restrict__ dst,
                                             const float* __restrict__ ew,
                                             const float* __restrict__ deg,
                                             int* __restrict__ cursor,
                                             uint2* __restrict__ edata,
                                             const unsigned short* __restrict__ xb,
                                             const unsigned short* __restrict__ W0t,
                                             const float* __restrict__ d0,
                                             unsigned short* __restrict__ tbufA) {
    __shared__ char smem[(128 * 72 + 128 * 72) * 2];    // 36864 B
    if (blockIdx.x < EB) {
        int i = blockIdx.x * 256 + threadIdx.x;
        if (i < NEDGE) {
            int s = src[i], d = dst[i];
            float ds = deg[s], dd = deg[d];
            float is = ds > 0.f ? rsqrtf(fmaxf(ds, EPSV)) : 0.f;
            float id = dd > 0.f ? rsqrtf(fmaxf(dd, EPSV)) : 0.f;
            float nm = is * ew[i] * id;
            int p = atomicAdd(&cursor[d], 1);
            edata[p] = make_uint2((unsigned)s, __builtin_bit_cast(unsigned, nm));
        }
        return;
    }
    mgemm_body<INDIM, HD, false, true>(blockIdx.x - EB, threadIdx.x, smem,
                                       xb, W0t, d0, tbufA, NN);
}

// ----------------------- agg2 + head BN stats (grid-strided, A2B blocks)
__global__ __launch_bounds__(256) void agg2_stats_k(const unsigned short* __restrict__ t,
                                                    const int* __restrict__ rowptr,
                                                    const uint2* __restrict__ edata,
                                                    const float* __restrict__ bias,
                                                    unsigned short* __restrict__ agg,
                                                    float* __restrict__ sums, int n) {
    const int tid = threadIdx.x, g = tid >> 4, gl = tid & 15;
    const unsigned short* tg = t + gl * 8;
    float4 bb0 = *(const float4*)&bias[gl * 8];
    float4 bb1 = *(const float4*)&bias[gl * 8 + 4];
    float ssum[8], ssq[8];
#pragma unroll
    for (int j = 0; j < 8; j++) { ssum[j] = 0.f; ssq[j] = 0.f; }

    for (int node0 = blockIdx.x * 16; node0 < n; node0 += A2B * 16) {
        int node = node0 + g;
        float acc[8];
#pragma unroll
        for (int j = 0; j < 8; j++) acc[j] = 0.f;
        if (node < n) {
            int beg = rowptr[node], end = rowptr[node + 1];
            for (int i = beg; i < end; i += 8)
                gather8(tg, edata, i, beg, end, acc);
        }
        float r[8];
        r[0] = fmaxf(acc[0] + bb0.x, 0.f); r[1] = fmaxf(acc[1] + bb0.y, 0.f);
        r[2] = fmaxf(acc[2] + bb0.z, 0.f); r[3] = fmaxf(acc[3] + bb0.w, 0.f);
        r[4] = fmaxf(acc[4] + bb1.x, 0.f); r[5] = fmaxf(acc[5] + bb1.y, 0.f);
        r[6] = fmaxf(acc[6] + bb1.z, 0.f); r[7] = fmaxf(acc[7] + bb1.w, 0.f);
        if (node < n) {
            uint4 o;
            o.x = (unsigned int)f2bf(r[0]) | ((unsigned int)f2bf(r[1]) << 16);
            o.y = (unsigned int)f2bf(r[2]) | ((unsigned int)f2bf(r[3]) << 16);
            o.z = (unsigned int)f2bf(r[4]) | ((unsigned int)f2bf(r[5]) << 16);
            o.w = (unsigned int)f2bf(r[6]) | ((unsigned int)f2bf(r[7]) << 16);
            *(uint4*)&agg[(size_t)node * HD + gl * 8] = o;
#pragma unroll
            for (int j = 0; j < 8; j++) { ssum[j] += r[j]; ssq[j] += r[j] * r[j]; }
        }
    }

    __shared__ float red[256 * 16];
#pragma unroll
    for (int j = 0; j < 8; j++) {
        red[tid * 16 + j]     = ssum[j];
        red[tid * 16 + 8 + j] = ssq[j];
    }
    __syncthreads();
    if (tid < HD) {                      // feature f = tid = glr*8 + j
        int glr = tid >> 3, j = tid & 7;
        float a = 0.f, b = 0.f;
#pragma unroll
        for (int g2 = 0; g2 < 16; g2++) {
            a += red[(g2 * 16 + glr) * 16 + j];
            b += red[(g2 * 16 + glr) * 16 + 8 + j];
        }
        atomAdd(&sums[tid], a);
        atomAdd(&sums[HD + tid], b);
    }
}

// ------------------------------------------------- combined head weight prep
__global__ __launch_bounds__(256) void wprep2_k(const float* __restrict__ stats2,
                                                const float* __restrict__ gamma,
                                                const float* __restrict__ beta,
                                                const float* __restrict__ pW,
                                                const float* __restrict__ pb,
                                                unsigned short* __restrict__ pWt,
                                                float* __restrict__ dfin, float invN) {
    __shared__ float sA[HD], sC[HD];
    int f = threadIdx.x;
    if (f < HD) {
        float mean = stats2[f] * invN;
        float var  = stats2[HD + f] * invN - mean * mean;
        float a    = gamma[f] * rsqrtf(var + EPSV);
        sA[f] = a;
        sC[f] = beta[f] - mean * a;
    }
    __syncthreads();
    int b = blockIdx.x, tid = threadIdx.x;
    if (b < 32) {                  // pW: 128x64, scale row k by sA[k]
        int i = b * 256 + tid, k = i >> 6, j = i & 63;
        pWt[(size_t)j * HD + k] = f2bf(pW[i] * sA[k]);
    } else {
        if (tid < OUTD) {
            float s = pb[tid];
            for (int ff = 0; ff < HD; ff++) s += sC[ff] * pW[ff * OUTD + tid];
            dfin[tid] = s;
        }
    }
}

// --------------------------------------------------------- standalone GEMM3
__global__ __launch_bounds__(256) void gemm3_k(const unsigned short* __restrict__ A,
                                               const unsigned short* __restrict__ Bt,
                                               const float* __restrict__ outBias,
                                               float* __restrict__ C, int n) {
    __shared__ char smem[(128 * 72 + OUTD * 72) * 2];   // 27648 B
    mgemm_body<HD, OUTD, true, false>(blockIdx.x, threadIdx.x, smem,
                                      A, Bt, outBias, C, n);
}

// ============================================================== host driver
extern "C" void kernel_launch(void* const* d_in, const int* in_sizes, int n_in,
                              void* d_out, int out_size, void* d_ws, size_t ws_size,
                              hipStream_t stream) {
    const float* x        = (const float*)d_in[0];
    const int*   ei       = (const int*)d_in[1];   // [2, E] int32
    const float* ew       = (const float*)d_in[2];
    const float* bn_gamma = (const float*)d_in[3];
    const float* bn_beta  = (const float*)d_in[4];
    const float* W0       = (const float*)d_in[5];
    const float* b0       = (const float*)d_in[6];
    const float* W1       = (const float*)d_in[7];
    const float* b1       = (const float*)d_in[8];
    const float* W2       = (const float*)d_in[9];
    const float* b2       = (const float*)d_in[10];
    const float* pgamma   = (const float*)d_in[11];
    const float* pbeta    = (const float*)d_in[12];
    const float* pW       = (const float*)d_in[13];
    const float* pb       = (const float*)d_in[14];
    float* out = (float*)d_out;

    const int* srcp = ei;
    const int* dstp = ei + NEDGE;

    char*  base = (char*)d_ws;
    size_t off  = 0;
    auto carve = [&](size_t bytes) -> void* {
        void* p = (void*)(base + off);
        off = (off + bytes + 255) & ~(size_t)255;
        return p;
    };
    // deg,cnt,stats,stats2 contiguous -> ONE memset
    float*          deg    = (float*)carve(NN * 4);
    int*            cnt    = (int*)carve(NN * 4);
    float*          stats  = (float*)carve(2 * INDIM * 4);
    float*          stats2 = (float*)carve(2 * HD * 4);
    int*            rowptr = (int*)carve((NN + 1) * 4);
    int*            cursor = (int*)carve(NN * 4);
    int*            bsum   = (int*)carve(512 * 4);
    uint2*          edata  = (uint2*)carve((size_t)NEDGE * 8);
    float*          d0     = (float*)carve(HD * 4);
    float*          dfin   = (float*)carve(OUTD * 4);
    unsigned short* W0t    = (unsigned short*)carve((size_t)INDIM * HD * 2);
    unsigned short* W1t    = (unsigned short*)carve((size_t)HD * HD * 2);
    unsigned short* W2t    = (unsigned short*)carve((size_t)HD * HD * 2);
    unsigned short* pWt    = (unsigned short*)carve((size_t)HD * OUTD * 2);
    unsigned short* xb     = (unsigned short*)carve((size_t)NN * INDIM * 2);
    unsigned short* tbufA  = (unsigned short*)carve((size_t)NN * HD * 2);
    unsigned short* tbufB  = (unsigned short*)carve((size_t)NN * HD * 2);
    unsigned short* aggb   = (unsigned short*)carve((size_t)NN * HD * 2);
    (void)ws_size;

    // ---- one memset over deg..stats2
    hipMemsetAsync(deg, 0, (size_t)((char*)stats2 - (char*)deg) + 2 * HD * 4, stream);

    // ---- front: deghist | bn_stats_x(+xb)
    front_k<<<EB + SB, 256, 0, stream>>>(dstp, ew, deg, cnt, x, stats, xb);

    // ---- mid: scan1 | wprep1
    mid_k<<<NB + WB, 256, 0, stream>>>(cnt, rowptr, bsum, stats, bn_gamma, bn_beta,
                                       W0, W1, W2, W0t, W1t, W2t, d0, 1.f / NN);
    scan2_k<<<1, 512, 0, stream>>>(bsum, NB);
    scan3_k<<<NB, 256, 0, stream>>>(rowptr, bsum, cursor, NN);

    // ---- scatter | GEMM0 (t0 = xb @ W0t + d0 -> tbufA)
    sg0_k<<<EB + GG, 256, 0, stream>>>(srcp, dstp, ew, deg, cursor, edata,
                                       xb, W0t, d0, tbufA);

    // ---- fused agg+GEMM layers 1,2
    fagg_gemm_k<<<GG, 256, 0, stream>>>(tbufA, rowptr, edata, b0, W1t, tbufB, NN);
    fagg_gemm_k<<<GG, 256, 0, stream>>>(tbufB, rowptr, edata, b1, W2t, tbufA, NN);

    // ---- agg2 + head BN stats
    agg2_stats_k<<<A2B, 256, 0, stream>>>(tbufA, rowptr, edata, b2, aggb, stats2, NN);

    // ---- head weight prep + GEMM3
    wprep2_k<<<33, 256, 0, stream>>>(stats2, pgamma, pbeta, pW, pb, pWt, dfin,
                                     1.f / NN);
    gemm3_k<<<GG, 256, 0, stream>>>(aggb, pWt, dfin, out, NN);

    (void)n_in; (void)in_sizes; (void)out_size;
}